// Round 1
// baseline (1000.637 us; speedup 1.0000x reference)
//
#include <hip/hip_runtime.h>
#include <hip/hip_bf16.h>

#define DEV __device__ __forceinline__

typedef __attribute__((ext_vector_type(4))) float f32x4;
typedef __attribute__((ext_vector_type(8))) short bf8_t;    // 8 bf16 = 4 VGPR
typedef __attribute__((ext_vector_type(4))) unsigned int u32x4;

// problem constants (fixed by setup_inputs)
static constexpr float QSCALE = 0.125f;   // dh^-0.5, dh=64

DEV float bflo(unsigned int w){ union{unsigned int i; float f;} x; x.i = w << 16; return x.f; }
DEV float bfhi(unsigned int w){ union{unsigned int i; float f;} x; x.i = w & 0xffff0000u; return x.f; }
DEV float bf2f(unsigned short u){ union{unsigned int i; float f;} x; x.i = ((unsigned int)u) << 16; return x.f; }
DEV unsigned short f2bf(float f){
  union{float f; unsigned int i;} x; x.f = f;
  unsigned int i = x.i;
  i += 0x7fffu + ((i >> 16) & 1u);   // round-to-nearest-even
  return (unsigned short)(i >> 16);
}
DEV unsigned int pack2(float a, float b){ return (unsigned int)f2bf(a) | ((unsigned int)f2bf(b) << 16); }

// inline-asm MFMA: D accumulates into C (tied operand) — avoids builtin type-signature risk
DEV void mfma_acc(f32x4& c, const bf8_t& a, const bf8_t& b){
  asm volatile("v_mfma_f32_16x16x32_bf16 %0, %1, %2, %0" : "+v"(c) : "v"(a), "v"(b));
}

DEV float wred_max(float v){
  #pragma unroll
  for (int m = 1; m < 64; m <<= 1) v = fmaxf(v, __shfl_xor(v, m));
  return v;
}
DEV float wred_sum(float v){
  #pragma unroll
  for (int m = 1; m < 64; m <<= 1) v += __shfl_xor(v, m);
  return v;
}

// ---------------- prep: weight transpose+convert, bias concat ----------------
__global__ void k_prep(const float* __restrict__ qw, const float* __restrict__ kvw,
                       const float* __restrict__ pw, const float* __restrict__ qb,
                       const float* __restrict__ kvb,
                       unsigned short* __restrict__ wqkvt, unsigned short* __restrict__ wprojt,
                       float* __restrict__ qkvbias){
  const int i0 = blockIdx.x * blockDim.x + threadIdx.x;
  const int stride = gridDim.x * blockDim.x;
  for (int idx = i0; idx < 1536*512; idx += stride){
    int n = idx >> 9, k = idx & 511;
    float v = (n < 512) ? qw[k*512 + n] : kvw[k*1024 + (n - 512)];
    wqkvt[idx] = f2bf(v);                      // wqkvt[n][k]
  }
  for (int idx = i0; idx < 512*512; idx += stride){
    int n = idx >> 9, k = idx & 511;
    wprojt[idx] = f2bf(pw[k*512 + n]);         // wprojt[n][k]
  }
  for (int idx = i0; idx < 1536; idx += stride)
    qkvbias[idx] = (idx < 512) ? qb[idx] : kvb[idx - 512];
}

// ---------------- x -> bf16 ----------------
__global__ void k_cvt_x(const float* __restrict__ x, unsigned short* __restrict__ xb){
  const long total8 = (long)50176*512/8;
  for (long i = (long)blockIdx.x*blockDim.x + threadIdx.x; i < total8; i += (long)gridDim.x*blockDim.x){
    const float4* p = (const float4*)(x + i*8);
    float4 a = p[0], b = p[1];
    u32x4 o;
    o.x = pack2(a.x, a.y); o.y = pack2(a.z, a.w);
    o.z = pack2(b.x, b.y); o.w = pack2(b.z, b.w);
    *(u32x4*)(xb + i*8) = o;
  }
}

// ---------------- GEMM: C[M,N] = A[M,512] * Bt[N,512]^T + bias ----------------
// 128x128 tile, 4 waves (2x2 of 64x64), 16x16x32 bf16 MFMA, padded LDS, reg-staging.
template<bool OUT_BF>
__global__ __launch_bounds__(256) void k_gemm(const unsigned short* __restrict__ A,
    const unsigned short* __restrict__ Bt, const float* __restrict__ bias,
    void* __restrict__ Cp, const int N){
  __shared__ unsigned short Al[128][40];  // pad 32->40: conflict-free b128 reads
  __shared__ unsigned short Bl[128][40];
  const int tid = threadIdx.x, lane = tid & 63, w = tid >> 6;
  const int m0 = blockIdx.y * 128, n0 = blockIdx.x * 128;
  const int wr = (w >> 1) * 64, wc = (w & 1) * 64;
  const int fr = lane & 15, kg = lane >> 4;
  f32x4 acc[4][4] = {};
  for (int kt = 0; kt < 16; ++kt){
    const int k0 = kt * 32;
    __syncthreads();
    #pragma unroll
    for (int cc = 0; cc < 2; ++cc){
      const int c = tid + cc*256;
      const int row = c >> 2, kb = c & 3;
      u32x4 va = *(const u32x4*)(A  + (size_t)(m0 + row)*512 + k0 + kb*8);
      u32x4 vb = *(const u32x4*)(Bt + (size_t)(n0 + row)*512 + k0 + kb*8);
      *(u32x4*)&Al[row][kb*8] = va;
      *(u32x4*)&Bl[row][kb*8] = vb;
    }
    __syncthreads();
    bf8_t af[4], bfm[4];
    #pragma unroll
    for (int i = 0; i < 4; ++i){
      af[i]  = *(const bf8_t*)&Al[wr + i*16 + fr][kg*8];
      bfm[i] = *(const bf8_t*)&Bl[wc + i*16 + fr][kg*8];
    }
    #pragma unroll
    for (int i = 0; i < 4; ++i)
      #pragma unroll
      for (int j = 0; j < 4; ++j)
        mfma_acc(acc[i][j], af[i], bfm[j]);
  }
  const int rb = (lane >> 4) * 4;
  #pragma unroll
  for (int j = 0; j < 4; ++j){
    const int col = n0 + wc + j*16 + fr;
    const float bs = bias[col];
    #pragma unroll
    for (int i = 0; i < 4; ++i){
      #pragma unroll
      for (int r = 0; r < 4; ++r){
        const int row = m0 + wr + i*16 + rb + r;
        float v = acc[i][j][r] + bs;
        if (OUT_BF) ((unsigned short*)Cp)[(size_t)row*N + col] = f2bf(v);
        else        ((float*)Cp)[(size_t)row*N + col] = v;
      }
    }
  }
}

// ---------------- agent pooling: 8x8 mean of q ----------------
__global__ void k_pool(const unsigned short* __restrict__ qkv, float* __restrict__ agent){
  const int b = blockIdx.x / 49, a = blockIdx.x % 49;
  const int p1 = a / 7, p2 = a % 7;
  for (int c = threadIdx.x; c < 512; c += 256){
    float s = 0.f;
    for (int r = 0; r < 8; ++r)
      for (int cc = 0; cc < 8; ++cc){
        int pix = (p1*8 + r)*56 + p2*8 + cc;
        s += bf2f(qkv[((size_t)b*3136 + pix)*1536 + c]);
      }
    agent[((size_t)b*49 + a)*512 + c] = s * (1.0f/64.0f);
  }
}

// ---------------- bilinear 7->56 helper ----------------
DEV void lin_w(int o, int& i0, int& i1, float& w){
  float src = (o + 0.5f)*0.125f - 0.5f;
  src = fmaxf(src, 0.f);
  int f = (int)floorf(src);
  i0 = min(f, 6); i1 = min(i0 + 1, 6); w = src - (float)i0;
}

// pb_sum[h][a][n] = resize(an_bias)[h,a,n] + ah_bias[h,a,y] + aw_bias[h,a,x]
__global__ void k_pb(const float* __restrict__ an, const float* __restrict__ ahb,
                     const float* __restrict__ awb, float* __restrict__ pbs){
  const int tot = 8*49*3136;
  for (int idx = blockIdx.x*blockDim.x + threadIdx.x; idx < tot; idx += gridDim.x*blockDim.x){
    int n = idx % 3136, ha = idx / 3136;
    int y = n / 56, x = n % 56;
    int iy0, iy1, ix0, ix1; float wy, wx;
    lin_w(y, iy0, iy1, wy); lin_w(x, ix0, ix1, wx);
    const float* t = an + (size_t)ha*49;
    float v0 = t[iy0*7+ix0]*(1.f-wy) + t[iy1*7+ix0]*wy;
    float v1 = t[iy0*7+ix1]*(1.f-wy) + t[iy1*7+ix1]*wy;
    float v = v0*(1.f-wx) + v1*wx;
    pbs[idx] = v + ahb[ha*56 + y] + awb[ha*56 + x];
  }
}

// ab_sum[h][n][a] = resize(na_bias)[h,a,n] + ha_bias[h,y,a] + wa_bias[h,x,a]
__global__ void k_ab(const float* __restrict__ na, const float* __restrict__ hab,
                     const float* __restrict__ wab, float* __restrict__ absum){
  const int tot = 8*49*3136;
  for (int idx = blockIdx.x*blockDim.x + threadIdx.x; idx < tot; idx += gridDim.x*blockDim.x){
    int n = idx % 3136, ha = idx / 3136;
    int a = ha % 49, h = ha / 49;
    int y = n / 56, x = n % 56;
    int iy0, iy1, ix0, ix1; float wy, wx;
    lin_w(y, iy0, iy1, wy); lin_w(x, ix0, ix1, wx);
    const float* t = na + (size_t)ha*49;
    float v0 = t[iy0*7+ix0]*(1.f-wy) + t[iy1*7+ix0]*wy;
    float v1 = t[iy0*7+ix1]*(1.f-wy) + t[iy1*7+ix1]*wy;
    float v = v0*(1.f-wx) + v1*wx;
    absum[((size_t)h*3136 + n)*49 + a] = v + hab[(h*56+y)*49 + a] + wab[(h*56+x)*49 + a];
  }
}

// ---------------- s1: agent attention, flash-style over n, split 8 ----------------
// grid: 16*8*8 blocks (b,h,s), 256 thr; wave w owns agents a = ai*4+w
__global__ __launch_bounds__(256) void k_attn1(const unsigned short* __restrict__ qkv,
    const float* __restrict__ agent, const float* __restrict__ pbs,
    float* __restrict__ pacc, float* __restrict__ pml){
  const int bi = blockIdx.x;
  const int s = bi & 7, h = (bi >> 3) & 7, b = bi >> 6;
  const int tid = threadIdx.x, lane = tid & 63, w = tid >> 6;
  __shared__ float ah[49][68];            // scaled agent
  __shared__ unsigned short kl[98][72];   // pad 64->72 (conflict-free b128)
  __shared__ unsigned short vl[98][72];
  __shared__ float pl[4][13][98];
  for (int i = tid; i < 49*64; i += 256){
    int a = i >> 6, d = i & 63;
    ah[a][d] = QSCALE * agent[((size_t)b*49 + a)*512 + h*64 + d];
  }
  float m_[13], l_[13], acc[13];
  #pragma unroll
  for (int ai = 0; ai < 13; ++ai){ m_[ai] = -1e30f; l_[ai] = 0.f; acc[ai] = 0.f; }
  const int p1ok = lane < 34;             // 64+lane < 98
  const int p1idx = p1ok ? 64 + lane : 97;
  for (int t = 0; t < 4; ++t){
    const int gn0 = s*392 + t*98;
    __syncthreads();
    for (int c = tid; c < 784; c += 256){
      int row = c >> 3, o = c & 7;
      const unsigned short* kp = qkv + ((size_t)b*3136 + gn0 + row)*1536 + 512 + h*64 + o*8;
      *(u32x4*)&kl[row][o*8] = *(const u32x4*)kp;
      *(u32x4*)&vl[row][o*8] = *(const u32x4*)(kp + 512);
    }
    __syncthreads();
    #pragma unroll
    for (int ai = 0; ai < 13; ++ai){
      const int a = ai*4 + w;
      if (a < 49){
        float s0 = 0.f, s1 = 0.f;
        #pragma unroll
        for (int d0 = 0; d0 < 8; ++d0){
          f32x4 alo = *(const f32x4*)&ah[a][d0*8];
          f32x4 ahi = *(const f32x4*)&ah[a][d0*8 + 4];
          u32x4 kv0 = *(const u32x4*)&kl[lane][d0*8];
          u32x4 kv1 = *(const u32x4*)&kl[p1idx][d0*8];
          s0 += alo.x*bflo(kv0.x) + alo.y*bfhi(kv0.x) + alo.z*bflo(kv0.y) + alo.w*bfhi(kv0.y)
              + ahi.x*bflo(kv0.z) + ahi.y*bfhi(kv0.z) + ahi.z*bflo(kv0.w) + ahi.w*bfhi(kv0.w);
          s1 += alo.x*bflo(kv1.x) + alo.y*bfhi(kv1.x) + alo.z*bflo(kv1.y) + alo.w*bfhi(kv1.y)
              + ahi.x*bflo(kv1.z) + ahi.y*bfhi(kv1.z) + ahi.z*bflo(kv1.w) + ahi.w*bfhi(kv1.w);
        }
        const float* pb = pbs + ((size_t)(h*49 + a))*3136 + gn0;
        s0 += pb[lane];
        s1 = p1ok ? (s1 + pb[64 + lane]) : -1e30f;
        float mx = wred_max(fmaxf(s0, s1));
        float mn = fmaxf(m_[ai], mx);
        float al = __expf(m_[ai] - mn);
        float p0 = __expf(s0 - mn);
        float p1 = p1ok ? __expf(s1 - mn) : 0.f;
        float rs = wred_sum(p0 + p1);
        m_[ai] = mn;
        l_[ai] = l_[ai]*al + rs;
        acc[ai] *= al;
        pl[w][ai][lane] = p0;
        if (p1ok) pl[w][ai][64 + lane] = p1;
      }
    }
    __syncthreads();
    for (int np = 0; np < 98; ++np){
      float vj = bf2f(vl[np][lane]);
      #pragma unroll
      for (int ai = 0; ai < 13; ++ai){
        if (ai*4 + w < 49) acc[ai] += pl[w][ai][np] * vj;
      }
    }
  }
  const int base = ((b*8 + h)*8 + s)*49;
  #pragma unroll
  for (int ai = 0; ai < 13; ++ai){
    const int a = ai*4 + w;
    if (a < 49){
      pacc[(size_t)(base + a)*64 + lane] = acc[ai];
      if (lane == 0){ pml[(base + a)*2] = m_[ai]; pml[(base + a)*2 + 1] = l_[ai]; }
    }
  }
}

// ---------------- merge the 8 partial softmax states -> agent_v ----------------
__global__ void k_merge(const float* __restrict__ pacc, const float* __restrict__ pml,
                        float* __restrict__ agentv){
  const int gw = blockIdx.x*4 + (threadIdx.x >> 6);
  const int lane = threadIdx.x & 63;
  if (gw >= 16*8*49) return;
  const int a = gw % 49, bh = gw / 49;
  float ms[8], ls[8], M = -1e30f;
  #pragma unroll
  for (int s = 0; s < 8; ++s){
    int base = (bh*8 + s)*49 + a;
    ms[s] = pml[base*2]; ls[s] = pml[base*2 + 1];
    M = fmaxf(M, ms[s]);
  }
  float L = 0.f, o = 0.f;
  #pragma unroll
  for (int s = 0; s < 8; ++s){
    float e = __expf(ms[s] - M);
    L += ls[s]*e;
    o += pacc[(size_t)((bh*8 + s)*49 + a)*64 + lane]*e;
  }
  agentv[(size_t)(bh*49 + a)*64 + lane] = o / L;
}

// ---------------- s2: q attention (49-wide softmax) + PV -> out (bf16) ----------------
__global__ __launch_bounds__(256) void k_attn2(const unsigned short* __restrict__ qkv,
    const float* __restrict__ agent, const float* __restrict__ agentv,
    const float* __restrict__ absum, unsigned short* __restrict__ outb){
  const int bi = blockIdx.x;
  const int s = bi & 7, h = (bi >> 3) & 7, b = bi >> 6;
  const int tid = threadIdx.x, lane = tid & 63, w = tid >> 6;
  __shared__ float ags[49][68];
  __shared__ float av[49][68];
  __shared__ float qs[4][64];
  __shared__ float ps[4][64];
  for (int i = tid; i < 49*64; i += 256){
    int a = i >> 6, d = i & 63;
    ags[a][d] = QSCALE * agent[((size_t)b*49 + a)*512 + h*64 + d];
    av[a][d]  = agentv[((size_t)((b*8 + h)*49) + a)*64 + d];
  }
  __syncthreads();
  for (int pp = 0; pp < 98; ++pp){
    const int pix = s*392 + w*98 + pp;
    float qd = bf2f(qkv[((size_t)b*3136 + pix)*1536 + h*64 + lane]);
    qs[w][lane] = qd;
    __syncthreads();
    const int a = lane < 49 ? lane : 48;
    float sc = 0.f;
    #pragma unroll
    for (int d0 = 0; d0 < 16; ++d0){
      f32x4 q4 = *(const f32x4*)&qs[w][d0*4];
      f32x4 g4 = *(const f32x4*)&ags[a][d0*4];
      sc += q4.x*g4.x + q4.y*g4.y + q4.z*g4.z + q4.w*g4.w;
    }
    sc += absum[((size_t)h*3136 + pix)*49 + a];
    if (lane >= 49) sc = -1e30f;
    float mx = wred_max(sc);
    float pv = lane < 49 ? __expf(sc - mx) : 0.f;
    float sm = wred_sum(pv);
    ps[w][lane] = pv / sm;
    __syncthreads();
    float o = 0.f;
    #pragma unroll
    for (int aa = 0; aa < 49; ++aa)
      o += ps[w][aa] * av[aa][lane];
    outb[((size_t)b*3136 + pix)*512 + h*64 + lane] = f2bf(o);
  }
}

// ---------------- depthwise 3x3 on v, RMW-add into outb ----------------
__global__ __launch_bounds__(256) void k_dwc(const unsigned short* __restrict__ qkv,
    const float* __restrict__ dwcw, const float* __restrict__ dwcb,
    unsigned short* __restrict__ outb){
  const int b = blockIdx.x / 56, y = blockIdx.x % 56;
  const int tid = threadIdx.x;
  const int cg = tid & 127, xh = tid >> 7;
  const int c0 = cg*4;
  float wv[9][4], bv[4];
  #pragma unroll
  for (int j = 0; j < 4; ++j){
    bv[j] = dwcb[c0 + j];
    #pragma unroll
    for (int t = 0; t < 9; ++t) wv[t][j] = dwcw[(c0 + j)*9 + t];
  }
  for (int xi = 0; xi < 28; ++xi){
    const int x = xh*28 + xi;
    float o[4] = {bv[0], bv[1], bv[2], bv[3]};
    #pragma unroll
    for (int ky = 0; ky < 3; ++ky){
      int ny = y + ky - 1;
      if (ny < 0 || ny >= 56) continue;
      #pragma unroll
      for (int kx = 0; kx < 3; ++kx){
        int nx = x + kx - 1;
        if (nx < 0 || nx >= 56) continue;
        const unsigned short* vp = qkv + ((size_t)b*3136 + ny*56 + nx)*1536 + 1024 + c0;
        unsigned int v01 = *(const unsigned int*)vp;
        unsigned int v23 = *((const unsigned int*)vp + 1);
        const int t = ky*3 + kx;
        o[0] += wv[t][0]*bflo(v01); o[1] += wv[t][1]*bfhi(v01);
        o[2] += wv[t][2]*bflo(v23); o[3] += wv[t][3]*bfhi(v23);
      }
    }
    unsigned short* op = outb + ((size_t)b*3136 + y*56 + x)*512 + c0;
    unsigned int a01 = *(unsigned int*)op;
    unsigned int a23 = *((unsigned int*)op + 1);
    o[0] += bflo(a01); o[1] += bfhi(a01);
    o[2] += bflo(a23); o[3] += bfhi(a23);
    *(unsigned int*)op       = pack2(o[0], o[1]);
    *((unsigned int*)op + 1) = pack2(o[2], o[3]);
  }
}

extern "C" void kernel_launch(void* const* d_in, const int* in_sizes, int n_in,
                              void* d_out, int out_size, void* d_ws, size_t ws_size,
                              hipStream_t stream){
  const float* x       = (const float*)d_in[0];
  const float* q_w     = (const float*)d_in[3];
  const float* q_b     = (const float*)d_in[4];
  const float* kv_w    = (const float*)d_in[5];
  const float* kv_b    = (const float*)d_in[6];
  const float* proj_w  = (const float*)d_in[7];
  const float* proj_b  = (const float*)d_in[8];
  const float* dwc_w   = (const float*)d_in[9];
  const float* dwc_b   = (const float*)d_in[10];
  const float* an_bias = (const float*)d_in[11];
  const float* na_bias = (const float*)d_in[12];
  const float* ah_bias = (const float*)d_in[13];
  const float* aw_bias = (const float*)d_in[14];
  const float* ha_bias = (const float*)d_in[15];
  const float* wa_bias = (const float*)d_in[16];

  char* ws = (char*)d_ws;
  size_t off = 0;
  auto alloc = [&](size_t bytes) -> void* {
    void* p = ws + off;
    off += (bytes + 255) & ~(size_t)255;
    return p;
  };
  unsigned short* xb     = (unsigned short*)alloc((size_t)50176*512*2);
  unsigned short* qkv    = (unsigned short*)alloc((size_t)50176*1536*2);
  unsigned short* wqkvt  = (unsigned short*)alloc((size_t)1536*512*2);
  unsigned short* wprojt = (unsigned short*)alloc((size_t)512*512*2);
  float* qkvb   = (float*)alloc((size_t)1536*4);
  float* agent  = (float*)alloc((size_t)16*49*512*4);
  float* agentv = (float*)alloc((size_t)16*8*49*64*4);
  float* pbs    = (float*)alloc((size_t)8*49*3136*4);
  float* absum  = (float*)alloc((size_t)8*3136*49*4);
  float* pacc   = (float*)alloc((size_t)16*8*8*49*64*4);
  float* pml    = (float*)alloc((size_t)16*8*8*49*2*4);
  unsigned short* outb = (unsigned short*)alloc((size_t)50176*512*2);
  if (off > ws_size) return;   // workspace too small -> fail validation visibly

  k_prep<<<512, 256, 0, stream>>>(q_w, kv_w, proj_w, q_b, kv_b, wqkvt, wprojt, qkvb);
  k_cvt_x<<<2048, 256, 0, stream>>>(x, xb);
  dim3 g1(12, 392);
  k_gemm<true><<<g1, 256, 0, stream>>>(xb, wqkvt, qkvb, qkv, 1536);
  k_pool<<<784, 256, 0, stream>>>(qkv, agent);
  k_pb<<<1024, 256, 0, stream>>>(an_bias, ah_bias, aw_bias, pbs);
  k_ab<<<1024, 256, 0, stream>>>(na_bias, ha_bias, wa_bias, absum);
  k_attn1<<<1024, 256, 0, stream>>>(qkv, agent, pbs, pacc, pml);
  k_merge<<<1568, 256, 0, stream>>>(pacc, pml, agentv);
  k_attn2<<<1024, 256, 0, stream>>>(qkv, agent, agentv, absum, outb);
  k_dwc<<<896, 256, 0, stream>>>(qkv, dwc_w, dwc_b, outb);
  dim3 g2(4, 392);
  k_gemm<false><<<g2, 256, 0, stream>>>(outb, wprojt, proj_b, d_out, 512);
}

// Round 2
// 694.913 us; speedup vs baseline: 1.4399x; 1.4399x over previous
//
#include <hip/hip_runtime.h>
#include <hip/hip_bf16.h>

#define DEV __device__ __forceinline__

typedef __attribute__((ext_vector_type(4))) float f32x4;
typedef __attribute__((ext_vector_type(8))) short bf8_t;    // 8 bf16 = 4 VGPR
typedef __attribute__((ext_vector_type(4))) unsigned int u32x4;

// problem constants (fixed by setup_inputs)
static constexpr float QSCALE = 0.125f;   // dh^-0.5, dh=64

DEV float bflo(unsigned int w){ union{unsigned int i; float f;} x; x.i = w << 16; return x.f; }
DEV float bfhi(unsigned int w){ union{unsigned int i; float f;} x; x.i = w & 0xffff0000u; return x.f; }
DEV float bf2f(unsigned short u){ union{unsigned int i; float f;} x; x.i = ((unsigned int)u) << 16; return x.f; }
DEV unsigned short f2bf(float f){
  union{float f; unsigned int i;} x; x.f = f;
  unsigned int i = x.i;
  i += 0x7fffu + ((i >> 16) & 1u);   // round-to-nearest-even
  return (unsigned short)(i >> 16);
}
DEV unsigned int pack2(float a, float b){ return (unsigned int)f2bf(a) | ((unsigned int)f2bf(b) << 16); }

// inline-asm MFMA: D accumulates into C (tied operand)
DEV void mfma_acc(f32x4& c, const bf8_t& a, const bf8_t& b){
  asm volatile("v_mfma_f32_16x16x32_bf16 %0, %1, %2, %0" : "+v"(c) : "v"(a), "v"(b));
}

DEV float wred_max(float v){
  #pragma unroll
  for (int m = 1; m < 64; m <<= 1) v = fmaxf(v, __shfl_xor(v, m));
  return v;
}
DEV float wred_sum(float v){
  #pragma unroll
  for (int m = 1; m < 64; m <<= 1) v += __shfl_xor(v, m);
  return v;
}

// ---------------- prep: weight transpose+convert, bias concat ----------------
__global__ void k_prep(const float* __restrict__ qw, const float* __restrict__ kvw,
                       const float* __restrict__ pw, const float* __restrict__ qb,
                       const float* __restrict__ kvb,
                       unsigned short* __restrict__ wqkvt, unsigned short* __restrict__ wprojt,
                       float* __restrict__ qkvbias){
  const int i0 = blockIdx.x * blockDim.x + threadIdx.x;
  const int stride = gridDim.x * blockDim.x;
  for (int idx = i0; idx < 1536*512; idx += stride){
    int n = idx >> 9, k = idx & 511;
    float v = (n < 512) ? qw[k*512 + n] : kvw[k*1024 + (n - 512)];
    wqkvt[idx] = f2bf(v);                      // wqkvt[n][k]
  }
  for (int idx = i0; idx < 512*512; idx += stride){
    int n = idx >> 9, k = idx & 511;
    wprojt[idx] = f2bf(pw[k*512 + n]);         // wprojt[n][k]
  }
  for (int idx = i0; idx < 1536; idx += stride)
    qkvbias[idx] = (idx < 512) ? qb[idx] : kvb[idx - 512];
}

// ---------------- x -> bf16 ----------------
__global__ void k_cvt_x(const float* __restrict__ x, unsigned short* __restrict__ xb){
  const long total8 = (long)50176*512/8;
  for (long i = (long)blockIdx.x*blockDim.x + threadIdx.x; i < total8; i += (long)gridDim.x*blockDim.x){
    const float4* p = (const float4*)(x + i*8);
    float4 a = p[0], b = p[1];
    u32x4 o;
    o.x = pack2(a.x, a.y); o.y = pack2(a.z, a.w);
    o.z = pack2(b.x, b.y); o.w = pack2(b.z, b.w);
    *(u32x4*)(xb + i*8) = o;
  }
}

// ---------------- GEMM: C[M,N] = A[M,512] * Bt[N,512]^T + bias ----------------
template<bool OUT_BF>
__global__ __launch_bounds__(256) void k_gemm(const unsigned short* __restrict__ A,
    const unsigned short* __restrict__ Bt, const float* __restrict__ bias,
    void* __restrict__ Cp, const int N){
  __shared__ unsigned short Al[128][40];
  __shared__ unsigned short Bl[128][40];
  const int tid = threadIdx.x, lane = tid & 63, w = tid >> 6;
  const int m0 = blockIdx.y * 128, n0 = blockIdx.x * 128;
  const int wr = (w >> 1) * 64, wc = (w & 1) * 64;
  const int fr = lane & 15, kg = lane >> 4;
  f32x4 acc[4][4] = {};
  for (int kt = 0; kt < 16; ++kt){
    const int k0 = kt * 32;
    __syncthreads();
    #pragma unroll
    for (int cc = 0; cc < 2; ++cc){
      const int c = tid + cc*256;
      const int row = c >> 2, kb = c & 3;
      u32x4 va = *(const u32x4*)(A  + (size_t)(m0 + row)*512 + k0 + kb*8);
      u32x4 vb = *(const u32x4*)(Bt + (size_t)(n0 + row)*512 + k0 + kb*8);
      *(u32x4*)&Al[row][kb*8] = va;
      *(u32x4*)&Bl[row][kb*8] = vb;
    }
    __syncthreads();
    bf8_t af[4], bfm[4];
    #pragma unroll
    for (int i = 0; i < 4; ++i){
      af[i]  = *(const bf8_t*)&Al[wr + i*16 + fr][kg*8];
      bfm[i] = *(const bf8_t*)&Bl[wc + i*16 + fr][kg*8];
    }
    #pragma unroll
    for (int i = 0; i < 4; ++i)
      #pragma unroll
      for (int j = 0; j < 4; ++j)
        mfma_acc(acc[i][j], af[i], bfm[j]);
  }
  const int rb = (lane >> 4) * 4;
  #pragma unroll
  for (int j = 0; j < 4; ++j){
    const int col = n0 + wc + j*16 + fr;
    const float bs = bias[col];
    #pragma unroll
    for (int i = 0; i < 4; ++i){
      #pragma unroll
      for (int r = 0; r < 4; ++r){
        const int row = m0 + wr + i*16 + rb + r;
        float v = acc[i][j][r] + bs;
        if (OUT_BF) ((unsigned short*)Cp)[(size_t)row*N + col] = f2bf(v);
        else        ((float*)Cp)[(size_t)row*N + col] = v;
      }
    }
  }
}

// ---------------- agent pooling: 8x8 mean of q ----------------
__global__ void k_pool(const unsigned short* __restrict__ qkv, float* __restrict__ agent){
  const int b = blockIdx.x / 49, a = blockIdx.x % 49;
  const int p1 = a / 7, p2 = a % 7;
  for (int c = threadIdx.x; c < 512; c += 256){
    float s = 0.f;
    for (int r = 0; r < 8; ++r)
      for (int cc = 0; cc < 8; ++cc){
        int pix = (p1*8 + r)*56 + p2*8 + cc;
        s += bf2f(qkv[((size_t)b*3136 + pix)*1536 + c]);
      }
    agent[((size_t)b*49 + a)*512 + c] = s * (1.0f/64.0f);
  }
}

// ---------------- bilinear 7->56 helper ----------------
DEV void lin_w(int o, int& i0, int& i1, float& w){
  float src = (o + 0.5f)*0.125f - 0.5f;
  src = fmaxf(src, 0.f);
  int f = (int)floorf(src);
  i0 = min(f, 6); i1 = min(i0 + 1, 6); w = src - (float)i0;
}

__global__ void k_pb(const float* __restrict__ an, const float* __restrict__ ahb,
                     const float* __restrict__ awb, float* __restrict__ pbs){
  const int tot = 8*49*3136;
  for (int idx = blockIdx.x*blockDim.x + threadIdx.x; idx < tot; idx += gridDim.x*blockDim.x){
    int n = idx % 3136, ha = idx / 3136;
    int y = n / 56, x = n % 56;
    int iy0, iy1, ix0, ix1; float wy, wx;
    lin_w(y, iy0, iy1, wy); lin_w(x, ix0, ix1, wx);
    const float* t = an + (size_t)ha*49;
    float v0 = t[iy0*7+ix0]*(1.f-wy) + t[iy1*7+ix0]*wy;
    float v1 = t[iy0*7+ix1]*(1.f-wy) + t[iy1*7+ix1]*wy;
    float v = v0*(1.f-wx) + v1*wx;
    pbs[idx] = v + ahb[ha*56 + y] + awb[ha*56 + x];
  }
}

__global__ void k_ab(const float* __restrict__ na, const float* __restrict__ hab,
                     const float* __restrict__ wab, float* __restrict__ absum){
  const int tot = 8*49*3136;
  for (int idx = blockIdx.x*blockDim.x + threadIdx.x; idx < tot; idx += gridDim.x*blockDim.x){
    int n = idx % 3136, ha = idx / 3136;
    int a = ha % 49, h = ha / 49;
    int y = n / 56, x = n % 56;
    int iy0, iy1, ix0, ix1; float wy, wx;
    lin_w(y, iy0, iy1, wy); lin_w(x, ix0, ix1, wx);
    const float* t = na + (size_t)ha*49;
    float v0 = t[iy0*7+ix0]*(1.f-wy) + t[iy1*7+ix0]*wy;
    float v1 = t[iy0*7+ix1]*(1.f-wy) + t[iy1*7+ix1]*wy;
    float v = v0*(1.f-wx) + v1*wx;
    absum[((size_t)h*3136 + n)*49 + a] = v + hab[(h*56+y)*49 + a] + wab[(h*56+x)*49 + a];
  }
}

// ---------------- s1: agent attention via MFMA, flash over n, split 7 ----------------
// grid 16*8*7 (b,h,sp); 4 waves; wave w owns agents 16w..16w+15 (cols),
// per tile: S^T[64px x 64ag] = K·ag^T, online softmax per agent (in-lane+shfl),
// PV[16ag x 64d] = P^T·V with P via per-wave LDS round-trip, V staged transposed.
__global__ __launch_bounds__(256) void k_attn1(const unsigned short* __restrict__ qkv,
    const float* __restrict__ agent, const float* __restrict__ pbs,
    float* __restrict__ pacc, float* __restrict__ pml){
  const int bi = blockIdx.x;
  const int sp = bi % 7, h = (bi/7) & 7, b = bi / 56;
  const int tid = threadIdx.x, lane = tid & 63, w = tid >> 6;
  const int c = lane & 15, kg = lane >> 4;

  __shared__ unsigned short ag[64][72];     // scaled agents [agent][d], rows 49..63 zero
  __shared__ unsigned short Kl[64][72];     // K tile [pixel][d]
  __shared__ unsigned short Vt[64][72];     // V tile transposed [d][pixel]
  __shared__ unsigned short Pl[4][16][72];  // per-wave P^T [agent][pixel]

  for (int it = tid; it < 64*8; it += 256){
    int a = it >> 3, o = it & 7;
    u32x4 wv = {0,0,0,0};
    if (a < 49){
      const float* p = agent + ((size_t)b*49 + a)*512 + h*64 + o*8;
      f32x4 lo = *(const f32x4*)p, hi = *(const f32x4*)(p+4);
      wv.x = pack2(lo.x*QSCALE, lo.y*QSCALE);
      wv.y = pack2(lo.z*QSCALE, lo.w*QSCALE);
      wv.z = pack2(hi.x*QSCALE, hi.y*QSCALE);
      wv.w = pack2(hi.z*QSCALE, hi.w*QSCALE);
    }
    *(u32x4*)&ag[a][o*8] = wv;
  }
  __syncthreads();
  bf8_t agf[2];
  agf[0] = *(const bf8_t*)&ag[w*16 + c][kg*8];
  agf[1] = *(const bf8_t*)&ag[w*16 + c][kg*8 + 32];

  const int aw = w*16 + c;
  const int amin = aw < 49 ? aw : 48;
  const bool areal = aw < 49;
  const float* pbrow = pbs + ((size_t)(h*49 + amin))*3136 + sp*448;

  float m_ = -1e30f, l_ = 0.f;
  f32x4 acc[4] = {};   // PV accum: agent row 16w+4kg+r, d col 16j+c

  for (int t = 0; t < 7; ++t){
    const int gn0 = sp*448 + t*64;
    f32x4 pb4[4];
    #pragma unroll
    for (int i = 0; i < 4; ++i)
      pb4[i] = *(const f32x4*)(pbrow + t*64 + 16*i + 4*kg);

    __syncthreads();
    // stage K rows (coalesced: o inner)
    #pragma unroll
    for (int ii = 0; ii < 2; ++ii){
      int it = tid + ii*256;
      int pix = it >> 3, o = it & 7;
      const unsigned short* kp = qkv + ((size_t)b*3136 + gn0 + pix)*1536 + 512 + h*64 + o*8;
      *(u32x4*)&Kl[pix][o*8] = *(const u32x4*)kp;
    }
    // stage V transposed (pixel-major lanes: bank-conflict-free scalar writes)
    #pragma unroll
    for (int ii = 0; ii < 2; ++ii){
      int it = tid + ii*256;
      int pix = it & 63, o = it >> 6;  // o in 0..7 across the two iterations
      const unsigned short* vp = qkv + ((size_t)b*3136 + gn0 + pix)*1536 + 1024 + h*64 + o*8;
      u32x4 vv = *(const u32x4*)vp;
      unsigned int vals[4] = {vv.x, vv.y, vv.z, vv.w};
      #pragma unroll
      for (int q = 0; q < 4; ++q){
        Vt[o*8 + 2*q][pix]     = (unsigned short)(vals[q] & 0xffffu);
        Vt[o*8 + 2*q + 1][pix] = (unsigned short)(vals[q] >> 16);
      }
    }
    __syncthreads();

    // S^T = K · ag^T : frags i over pixel rows, 2 k-steps over d
    f32x4 sa[4] = {};
    #pragma unroll
    for (int i = 0; i < 4; ++i){
      bf8_t kf0 = *(const bf8_t*)&Kl[i*16 + c][kg*8];
      bf8_t kf1 = *(const bf8_t*)&Kl[i*16 + c][kg*8 + 32];
      mfma_acc(sa[i], kf0, agf[0]);
      mfma_acc(sa[i], kf1, agf[1]);
    }

    // online softmax per agent (=lane c); lane holds pixels 16i+4kg+r
    float s16[4][4]; float mx = -1e30f;
    #pragma unroll
    for (int i = 0; i < 4; ++i)
      #pragma unroll
      for (int r = 0; r < 4; ++r){
        float sv = areal ? (sa[i][r] + pb4[i][r]) : -1e30f;
        s16[i][r] = sv; mx = fmaxf(mx, sv);
      }
    mx = fmaxf(mx, __shfl_xor(mx, 16));
    mx = fmaxf(mx, __shfl_xor(mx, 32));
    float mn = fmaxf(m_, mx);
    float al = __expf(m_ - mn);
    float rs = 0.f;
    #pragma unroll
    for (int i = 0; i < 4; ++i)
      #pragma unroll
      for (int r = 0; r < 4; ++r){
        float p = __expf(s16[i][r] - mn);
        s16[i][r] = p; rs += p;
      }
    rs += __shfl_xor(rs, 16);
    rs += __shfl_xor(rs, 32);
    m_ = mn; l_ = l_*al + rs;

    // write P^T (wave-local, no barrier needed)
    #pragma unroll
    for (int i = 0; i < 4; ++i){
      uint2 pw;
      pw.x = pack2(s16[i][0], s16[i][1]);
      pw.y = pack2(s16[i][2], s16[i][3]);
      *(uint2*)&Pl[w][c][16*i + 4*kg] = pw;
    }

    // rescale acc rows by al of their agent (4kg+r within wave)
    float al_s[4];
    #pragma unroll
    for (int r = 0; r < 4; ++r) al_s[r] = __shfl(al, 4*kg + r);
    #pragma unroll
    for (int j = 0; j < 4; ++j)
      #pragma unroll
      for (int r = 0; r < 4; ++r) acc[j][r] *= al_s[r];

    // PV: acc[j] += P^T · V
    bf8_t pf0 = *(const bf8_t*)&Pl[w][c][kg*8];
    bf8_t pf1 = *(const bf8_t*)&Pl[w][c][kg*8 + 32];
    #pragma unroll
    for (int j = 0; j < 4; ++j){
      bf8_t vf0 = *(const bf8_t*)&Vt[j*16 + c][kg*8];
      bf8_t vf1 = *(const bf8_t*)&Vt[j*16 + c][kg*8 + 32];
      mfma_acc(acc[j], pf0, vf0);
      mfma_acc(acc[j], pf1, vf1);
    }
  }

  const int base = ((b*8 + h)*7 + sp)*49;
  #pragma unroll
  for (int r = 0; r < 4; ++r){
    const int a = w*16 + 4*kg + r;
    if (a < 49){
      float* dst = pacc + (size_t)(base + a)*64 + c;
      #pragma unroll
      for (int j = 0; j < 4; ++j) dst[16*j] = acc[j][r];
    }
  }
  if (kg == 0 && areal){
    pml[(base + aw)*2]     = m_;
    pml[(base + aw)*2 + 1] = l_;
  }
}

// ---------------- merge the 7 partial softmax states -> agent_v ----------------
__global__ void k_merge(const float* __restrict__ pacc, const float* __restrict__ pml,
                        float* __restrict__ agentv){
  const int gw = blockIdx.x*4 + (threadIdx.x >> 6);
  const int lane = threadIdx.x & 63;
  if (gw >= 16*8*49) return;
  const int a = gw % 49, bh = gw / 49;
  float ms[7], ls[7], M = -1e30f;
  #pragma unroll
  for (int s = 0; s < 7; ++s){
    int base = (bh*7 + s)*49 + a;
    ms[s] = pml[base*2]; ls[s] = pml[base*2 + 1];
    M = fmaxf(M, ms[s]);
  }
  float L = 0.f, o = 0.f;
  #pragma unroll
  for (int s = 0; s < 7; ++s){
    float e = __expf(ms[s] - M);
    L += ls[s]*e;
    o += pacc[(size_t)((bh*7 + s)*49 + a)*64 + lane]*e;
  }
  agentv[(size_t)(bh*49 + a)*64 + lane] = o / L;
}

// ---------------- s2: q attention (49-wide softmax) + PV -> out (bf16) ----------------
__global__ __launch_bounds__(256) void k_attn2(const unsigned short* __restrict__ qkv,
    const float* __restrict__ agent, const float* __restrict__ agentv,
    const float* __restrict__ absum, unsigned short* __restrict__ outb){
  const int bi = blockIdx.x;
  const int s = bi & 7, h = (bi >> 3) & 7, b = bi >> 6;
  const int tid = threadIdx.x, lane = tid & 63, w = tid >> 6;
  __shared__ float ags[49][68];
  __shared__ float av[49][68];
  __shared__ float qs[4][64];
  __shared__ float ps[4][64];
  for (int i = tid; i < 49*64; i += 256){
    int a = i >> 6, d = i & 63;
    ags[a][d] = QSCALE * agent[((size_t)b*49 + a)*512 + h*64 + d];
    av[a][d]  = agentv[((size_t)((b*8 + h)*49) + a)*64 + d];
  }
  __syncthreads();
  for (int pp = 0; pp < 98; ++pp){
    const int pix = s*392 + w*98 + pp;
    float qd = bf2f(qkv[((size_t)b*3136 + pix)*1536 + h*64 + lane]);
    qs[w][lane] = qd;
    __syncthreads();
    const int a = lane < 49 ? lane : 48;
    float sc = 0.f;
    #pragma unroll
    for (int d0 = 0; d0 < 16; ++d0){
      f32x4 q4 = *(const f32x4*)&qs[w][d0*4];
      f32x4 g4 = *(const f32x4*)&ags[a][d0*4];
      sc += q4.x*g4.x + q4.y*g4.y + q4.z*g4.z + q4.w*g4.w;
    }
    sc += absum[((size_t)h*3136 + pix)*49 + a];
    if (lane >= 49) sc = -1e30f;
    float mx = wred_max(sc);
    float pv = lane < 49 ? __expf(sc - mx) : 0.f;
    float sm = wred_sum(pv);
    ps[w][lane] = pv / sm;
    __syncthreads();
    float o = 0.f;
    #pragma unroll
    for (int aa = 0; aa < 49; ++aa)
      o += ps[w][aa] * av[aa][lane];
    outb[((size_t)b*3136 + pix)*512 + h*64 + lane] = f2bf(o);
  }
}

// ---------------- depthwise 3x3 on v, RMW-add into outb ----------------
__global__ __launch_bounds__(256) void k_dwc(const unsigned short* __restrict__ qkv,
    const float* __restrict__ dwcw, const float* __restrict__ dwcb,
    unsigned short* __restrict__ outb){
  const int b = blockIdx.x / 56, y = blockIdx.x % 56;
  const int tid = threadIdx.x;
  const int cg = tid & 127, xh = tid >> 7;
  const int c0 = cg*4;
  float wv[9][4], bv[4];
  #pragma unroll
  for (int j = 0; j < 4; ++j){
    bv[j] = dwcb[c0 + j];
    #pragma unroll
    for (int t = 0; t < 9; ++t) wv[t][j] = dwcw[(c0 + j)*9 + t];
  }
  for (int xi = 0; xi < 28; ++xi){
    const int x = xh*28 + xi;
    float o[4] = {bv[0], bv[1], bv[2], bv[3]};
    #pragma unroll
    for (int ky = 0; ky < 3; ++ky){
      int ny = y + ky - 1;
      if (ny < 0 || ny >= 56) continue;
      #pragma unroll
      for (int kx = 0; kx < 3; ++kx){
        int nx = x + kx - 1;
        if (nx < 0 || nx >= 56) continue;
        const unsigned short* vp = qkv + ((size_t)b*3136 + ny*56 + nx)*1536 + 1024 + c0;
        unsigned int v01 = *(const unsigned int*)vp;
        unsigned int v23 = *((const unsigned int*)vp + 1);
        const int t = ky*3 + kx;
        o[0] += wv[t][0]*bflo(v01); o[1] += wv[t][1]*bfhi(v01);
        o[2] += wv[t][2]*bflo(v23); o[3] += wv[t][3]*bfhi(v23);
      }
    }
    unsigned short* op = outb + ((size_t)b*3136 + y*56 + x)*512 + c0;
    unsigned int a01 = *(unsigned int*)op;
    unsigned int a23 = *((unsigned int*)op + 1);
    o[0] += bflo(a01); o[1] += bfhi(a01);
    o[2] += bflo(a23); o[3] += bfhi(a23);
    *(unsigned int*)op       = pack2(o[0], o[1]);
    *((unsigned int*)op + 1) = pack2(o[2], o[3]);
  }
}

extern "C" void kernel_launch(void* const* d_in, const int* in_sizes, int n_in,
                              void* d_out, int out_size, void* d_ws, size_t ws_size,
                              hipStream_t stream){
  const float* x       = (const float*)d_in[0];
  const float* q_w     = (const float*)d_in[3];
  const float* q_b     = (const float*)d_in[4];
  const float* kv_w    = (const float*)d_in[5];
  const float* kv_b    = (const float*)d_in[6];
  const float* proj_w  = (const float*)d_in[7];
  const float* proj_b  = (const float*)d_in[8];
  const float* dwc_w   = (const float*)d_in[9];
  const float* dwc_b   = (const float*)d_in[10];
  const float* an_bias = (const float*)d_in[11];
  const float* na_bias = (const float*)d_in[12];
  const float* ah_bias = (const float*)d_in[13];
  const float* aw_bias = (const float*)d_in[14];
  const float* ha_bias = (const float*)d_in[15];
  const float* wa_bias = (const float*)d_in[16];

  char* ws = (char*)d_ws;
  size_t off = 0;
  auto alloc = [&](size_t bytes) -> void* {
    void* p = ws + off;
    off += (bytes + 255) & ~(size_t)255;
    return p;
  };
  unsigned short* xb     = (unsigned short*)alloc((size_t)50176*512*2);
  unsigned short* qkv    = (unsigned short*)alloc((size_t)50176*1536*2);
  unsigned short* wqkvt  = (unsigned short*)alloc((size_t)1536*512*2);
  unsigned short* wprojt = (unsigned short*)alloc((size_t)512*512*2);
  float* qkvb   = (float*)alloc((size_t)1536*4);
  float* agent  = (float*)alloc((size_t)16*49*512*4);
  float* agentv = (float*)alloc((size_t)16*8*49*64*4);
  float* pbs    = (float*)alloc((size_t)8*49*3136*4);
  float* absum  = (float*)alloc((size_t)8*3136*49*4);
  float* pacc   = (float*)alloc((size_t)16*8*8*49*64*4);
  float* pml    = (float*)alloc((size_t)16*8*8*49*2*4);
  unsigned short* outb = (unsigned short*)alloc((size_t)50176*512*2);
  if (off > ws_size) return;

  k_prep<<<512, 256, 0, stream>>>(q_w, kv_w, proj_w, q_b, kv_b, wqkvt, wprojt, qkvb);
  k_cvt_x<<<2048, 256, 0, stream>>>(x, xb);
  dim3 g1(12, 392);
  k_gemm<true><<<g1, 256, 0, stream>>>(xb, wqkvt, qkvb, qkv, 1536);
  k_pool<<<784, 256, 0, stream>>>(qkv, agent);
  k_pb<<<1024, 256, 0, stream>>>(an_bias, ah_bias, aw_bias, pbs);
  k_ab<<<1024, 256, 0, stream>>>(na_bias, ha_bias, wa_bias, absum);
  k_attn1<<<896, 256, 0, stream>>>(qkv, agent, pbs, pacc, pml);
  k_merge<<<1568, 256, 0, stream>>>(pacc, pml, agentv);
  k_attn2<<<1024, 256, 0, stream>>>(qkv, agent, agentv, absum, outb);
  k_dwc<<<896, 256, 0, stream>>>(qkv, dwc_w, dwc_b, outb);
  dim3 g2(4, 392);
  k_gemm<false><<<g2, 256, 0, stream>>>(outb, wprojt, proj_b, d_out, 512);
}

// Round 4
// 414.755 us; speedup vs baseline: 2.4126x; 1.6755x over previous
//
#include <hip/hip_runtime.h>
#include <hip/hip_bf16.h>

#define DEV __device__ __forceinline__

typedef __attribute__((ext_vector_type(4))) float f32x4;
typedef __attribute__((ext_vector_type(8))) short bf8_t;    // 8 bf16 = 4 VGPR
typedef __attribute__((ext_vector_type(4))) unsigned int u32x4;

// problem constants (fixed by setup_inputs)
static constexpr float QSCALE = 0.125f;   // dh^-0.5, dh=64

DEV float bflo(unsigned int w){ union{unsigned int i; float f;} x; x.i = w << 16; return x.f; }
DEV float bfhi(unsigned int w){ union{unsigned int i; float f;} x; x.i = w & 0xffff0000u; return x.f; }
DEV float bf2f(unsigned short u){ union{unsigned int i; float f;} x; x.i = ((unsigned int)u) << 16; return x.f; }
DEV unsigned short f2bf(float f){
  union{float f; unsigned int i;} x; x.f = f;
  unsigned int i = x.i;
  i += 0x7fffu + ((i >> 16) & 1u);   // round-to-nearest-even
  return (unsigned short)(i >> 16);
}
DEV unsigned int pack2(float a, float b){ return (unsigned int)f2bf(a) | ((unsigned int)f2bf(b) << 16); }

// inline-asm MFMA: D accumulates into C (tied operand)
DEV void mfma_acc(f32x4& c, const bf8_t& a, const bf8_t& b){
  asm volatile("v_mfma_f32_16x16x32_bf16 %0, %1, %2, %0" : "+v"(c) : "v"(a), "v"(b));
}

DEV float wred_max(float v){
  #pragma unroll
  for (int m = 1; m < 64; m <<= 1) v = fmaxf(v, __shfl_xor(v, m));
  return v;
}
DEV float wred_sum(float v){
  #pragma unroll
  for (int m = 1; m < 64; m <<= 1) v += __shfl_xor(v, m);
  return v;
}

// ---------------- prep: weight transpose+convert, bias concat ----------------
__global__ void k_prep(const float* __restrict__ qw, const float* __restrict__ kvw,
                       const float* __restrict__ pw, const float* __restrict__ qb,
                       const float* __restrict__ kvb,
                       unsigned short* __restrict__ wqkvt, unsigned short* __restrict__ wprojt,
                       float* __restrict__ qkvbias){
  const int i0 = blockIdx.x * blockDim.x + threadIdx.x;
  const int stride = gridDim.x * blockDim.x;
  for (int idx = i0; idx < 1536*512; idx += stride){
    int n = idx >> 9, k = idx & 511;
    float v = (n < 512) ? qw[k*512 + n] : kvw[k*1024 + (n - 512)];
    wqkvt[idx] = f2bf(v);                      // wqkvt[n][k]
  }
  for (int idx = i0; idx < 512*512; idx += stride){
    int n = idx >> 9, k = idx & 511;
    wprojt[idx] = f2bf(pw[k*512 + n]);         // wprojt[n][k]
  }
  for (int idx = i0; idx < 1536; idx += stride)
    qkvbias[idx] = (idx < 512) ? qb[idx] : kvb[idx - 512];
}

// ---------------- x -> bf16 ----------------
__global__ void k_cvt_x(const float* __restrict__ x, unsigned short* __restrict__ xb){
  const long total8 = (long)50176*512/8;
  for (long i = (long)blockIdx.x*blockDim.x + threadIdx.x; i < total8; i += (long)gridDim.x*blockDim.x){
    const float4* p = (const float4*)(x + i*8);
    float4 a = p[0], b = p[1];
    u32x4 o;
    o.x = pack2(a.x, a.y); o.y = pack2(a.z, a.w);
    o.z = pack2(b.x, b.y); o.w = pack2(b.z, b.w);
    *(u32x4*)(xb + i*8) = o;
  }
}

// ---------------- GEMM: C[M,N] = A[M,512] * Bt[N,512]^T + bias ----------------
template<bool OUT_BF>
__global__ __launch_bounds__(256) void k_gemm(const unsigned short* __restrict__ A,
    const unsigned short* __restrict__ Bt, const float* __restrict__ bias,
    void* __restrict__ Cp, const int N){
  __shared__ unsigned short Al[128][40];
  __shared__ unsigned short Bl[128][40];
  const int tid = threadIdx.x, lane = tid & 63, w = tid >> 6;
  const int m0 = blockIdx.y * 128, n0 = blockIdx.x * 128;
  const int wr = (w >> 1) * 64, wc = (w & 1) * 64;
  const int fr = lane & 15, kg = lane >> 4;
  f32x4 acc[4][4] = {};
  for (int kt = 0; kt < 16; ++kt){
    const int k0 = kt * 32;
    __syncthreads();
    #pragma unroll
    for (int cc = 0; cc < 2; ++cc){
      const int c = tid + cc*256;
      const int row = c >> 2, kb = c & 3;
      u32x4 va = *(const u32x4*)(A  + (size_t)(m0 + row)*512 + k0 + kb*8);
      u32x4 vb = *(const u32x4*)(Bt + (size_t)(n0 + row)*512 + k0 + kb*8);
      *(u32x4*)&Al[row][kb*8] = va;
      *(u32x4*)&Bl[row][kb*8] = vb;
    }
    __syncthreads();
    bf8_t af[4], bfm[4];
    #pragma unroll
    for (int i = 0; i < 4; ++i){
      af[i]  = *(const bf8_t*)&Al[wr + i*16 + fr][kg*8];
      bfm[i] = *(const bf8_t*)&Bl[wc + i*16 + fr][kg*8];
    }
    #pragma unroll
    for (int i = 0; i < 4; ++i)
      #pragma unroll
      for (int j = 0; j < 4; ++j)
        mfma_acc(acc[i][j], af[i], bfm[j]);
  }
  const int rb = (lane >> 4) * 4;
  #pragma unroll
  for (int j = 0; j < 4; ++j){
    const int col = n0 + wc + j*16 + fr;
    const float bs = bias[col];
    #pragma unroll
    for (int i = 0; i < 4; ++i){
      #pragma unroll
      for (int r = 0; r < 4; ++r){
        const int row = m0 + wr + i*16 + rb + r;
        float v = acc[i][j][r] + bs;
        if (OUT_BF) ((unsigned short*)Cp)[(size_t)row*N + col] = f2bf(v);
        else        ((float*)Cp)[(size_t)row*N + col] = v;
      }
    }
  }
}

// ---------------- agent pooling: 8x8 mean of q ----------------
__global__ void k_pool(const unsigned short* __restrict__ qkv, float* __restrict__ agent){
  const int b = blockIdx.x / 49, a = blockIdx.x % 49;
  const int p1 = a / 7, p2 = a % 7;
  for (int c = threadIdx.x; c < 512; c += 256){
    float s = 0.f;
    for (int r = 0; r < 8; ++r)
      for (int cc = 0; cc < 8; ++cc){
        int pix = (p1*8 + r)*56 + p2*8 + cc;
        s += bf2f(qkv[((size_t)b*3136 + pix)*1536 + c]);
      }
    agent[((size_t)b*49 + a)*512 + c] = s * (1.0f/64.0f);
  }
}

// ---------------- bilinear 7->56 helper ----------------
DEV void lin_w(int o, int& i0, int& i1, float& w){
  float src = (o + 0.5f)*0.125f - 0.5f;
  src = fmaxf(src, 0.f);
  int f = (int)floorf(src);
  i0 = min(f, 6); i1 = min(i0 + 1, 6); w = src - (float)i0;
}

__global__ void k_pb(const float* __restrict__ an, const float* __restrict__ ahb,
                     const float* __restrict__ awb, float* __restrict__ pbs){
  const int tot = 8*49*3136;
  for (int idx = blockIdx.x*blockDim.x + threadIdx.x; idx < tot; idx += gridDim.x*blockDim.x){
    int n = idx % 3136, ha = idx / 3136;
    int y = n / 56, x = n % 56;
    int iy0, iy1, ix0, ix1; float wy, wx;
    lin_w(y, iy0, iy1, wy); lin_w(x, ix0, ix1, wx);
    const float* t = an + (size_t)ha*49;
    float v0 = t[iy0*7+ix0]*(1.f-wy) + t[iy1*7+ix0]*wy;
    float v1 = t[iy0*7+ix1]*(1.f-wy) + t[iy1*7+ix1]*wy;
    float v = v0*(1.f-wx) + v1*wx;
    pbs[idx] = v + ahb[ha*56 + y] + awb[ha*56 + x];
  }
}

// absumT[h][agent][pix]  (transposed layout: coalesced for MFMA-attn2 bias reads)
__global__ void k_ab(const float* __restrict__ na, const float* __restrict__ hab,
                     const float* __restrict__ wab, float* __restrict__ absumT){
  const int tot = 8*49*3136;
  for (int idx = blockIdx.x*blockDim.x + threadIdx.x; idx < tot; idx += gridDim.x*blockDim.x){
    int n = idx % 3136, ha = idx / 3136;
    int a = ha % 49, h = ha / 49;
    int y = n / 56, x = n % 56;
    int iy0, iy1, ix0, ix1; float wy, wx;
    lin_w(y, iy0, iy1, wy); lin_w(x, ix0, ix1, wx);
    const float* t = na + (size_t)ha*49;
    float v0 = t[iy0*7+ix0]*(1.f-wy) + t[iy1*7+ix0]*wy;
    float v1 = t[iy0*7+ix1]*(1.f-wy) + t[iy1*7+ix1]*wy;
    float v = v0*(1.f-wx) + v1*wx;
    absumT[idx] = v + hab[(h*56+y)*49 + a] + wab[(h*56+x)*49 + a];
  }
}

// ---------------- s1: agent attention via MFMA, flash over n, split 7 ----------------
__global__ __launch_bounds__(256) void k_attn1(const unsigned short* __restrict__ qkv,
    const float* __restrict__ agent, const float* __restrict__ pbs,
    float* __restrict__ pacc, float* __restrict__ pml){
  const int bi = blockIdx.x;
  const int sp = bi % 7, h = (bi/7) & 7, b = bi / 56;
  const int tid = threadIdx.x, lane = tid & 63, w = tid >> 6;
  const int c = lane & 15, kg = lane >> 4;

  __shared__ unsigned short ag[64][72];
  __shared__ unsigned short Kl[64][72];
  __shared__ unsigned short Vt[64][72];
  __shared__ unsigned short Pl[4][16][72];

  for (int it = tid; it < 64*8; it += 256){
    int a = it >> 3, o = it & 7;
    u32x4 wv = {0,0,0,0};
    if (a < 49){
      const float* p = agent + ((size_t)b*49 + a)*512 + h*64 + o*8;
      f32x4 lo = *(const f32x4*)p, hi = *(const f32x4*)(p+4);
      wv.x = pack2(lo.x*QSCALE, lo.y*QSCALE);
      wv.y = pack2(lo.z*QSCALE, lo.w*QSCALE);
      wv.z = pack2(hi.x*QSCALE, hi.y*QSCALE);
      wv.w = pack2(hi.z*QSCALE, hi.w*QSCALE);
    }
    *(u32x4*)&ag[a][o*8] = wv;
  }
  __syncthreads();
  bf8_t agf[2];
  agf[0] = *(const bf8_t*)&ag[w*16 + c][kg*8];
  agf[1] = *(const bf8_t*)&ag[w*16 + c][kg*8 + 32];

  const int aw = w*16 + c;
  const int amin = aw < 49 ? aw : 48;
  const bool areal = aw < 49;
  const float* pbrow = pbs + ((size_t)(h*49 + amin))*3136 + sp*448;

  float m_ = -1e30f, l_ = 0.f;
  f32x4 acc[4] = {};

  for (int t = 0; t < 7; ++t){
    const int gn0 = sp*448 + t*64;
    f32x4 pb4[4];
    #pragma unroll
    for (int i = 0; i < 4; ++i)
      pb4[i] = *(const f32x4*)(pbrow + t*64 + 16*i + 4*kg);

    __syncthreads();
    #pragma unroll
    for (int ii = 0; ii < 2; ++ii){
      int it = tid + ii*256;
      int pix = it >> 3, o = it & 7;
      const unsigned short* kp = qkv + ((size_t)b*3136 + gn0 + pix)*1536 + 512 + h*64 + o*8;
      *(u32x4*)&Kl[pix][o*8] = *(const u32x4*)kp;
    }
    #pragma unroll
    for (int ii = 0; ii < 2; ++ii){
      int it = tid + ii*256;
      int pix = it & 63, o = it >> 6;
      const unsigned short* vp = qkv + ((size_t)b*3136 + gn0 + pix)*1536 + 1024 + h*64 + o*8;
      u32x4 vv = *(const u32x4*)vp;
      unsigned int vals[4] = {vv.x, vv.y, vv.z, vv.w};
      #pragma unroll
      for (int q = 0; q < 4; ++q){
        Vt[o*8 + 2*q][pix]     = (unsigned short)(vals[q] & 0xffffu);
        Vt[o*8 + 2*q + 1][pix] = (unsigned short)(vals[q] >> 16);
      }
    }
    __syncthreads();

    f32x4 sa[4] = {};
    #pragma unroll
    for (int i = 0; i < 4; ++i){
      bf8_t kf0 = *(const bf8_t*)&Kl[i*16 + c][kg*8];
      bf8_t kf1 = *(const bf8_t*)&Kl[i*16 + c][kg*8 + 32];
      mfma_acc(sa[i], kf0, agf[0]);
      mfma_acc(sa[i], kf1, agf[1]);
    }

    float s16[4][4]; float mx = -1e30f;
    #pragma unroll
    for (int i = 0; i < 4; ++i)
      #pragma unroll
      for (int r = 0; r < 4; ++r){
        float sv = areal ? (sa[i][r] + pb4[i][r]) : -1e30f;
        s16[i][r] = sv; mx = fmaxf(mx, sv);
      }
    mx = fmaxf(mx, __shfl_xor(mx, 16));
    mx = fmaxf(mx, __shfl_xor(mx, 32));
    float mn = fmaxf(m_, mx);
    float al = __expf(m_ - mn);
    float rs = 0.f;
    #pragma unroll
    for (int i = 0; i < 4; ++i)
      #pragma unroll
      for (int r = 0; r < 4; ++r){
        float p = __expf(s16[i][r] - mn);
        s16[i][r] = p; rs += p;
      }
    rs += __shfl_xor(rs, 16);
    rs += __shfl_xor(rs, 32);
    m_ = mn; l_ = l_*al + rs;

    #pragma unroll
    for (int i = 0; i < 4; ++i){
      uint2 pw;
      pw.x = pack2(s16[i][0], s16[i][1]);
      pw.y = pack2(s16[i][2], s16[i][3]);
      *(uint2*)&Pl[w][c][16*i + 4*kg] = pw;
    }

    float al_s[4];
    #pragma unroll
    for (int r = 0; r < 4; ++r) al_s[r] = __shfl(al, 4*kg + r);
    #pragma unroll
    for (int j = 0; j < 4; ++j)
      #pragma unroll
      for (int r = 0; r < 4; ++r) acc[j][r] *= al_s[r];

    bf8_t pf0 = *(const bf8_t*)&Pl[w][c][kg*8];
    bf8_t pf1 = *(const bf8_t*)&Pl[w][c][kg*8 + 32];
    #pragma unroll
    for (int j = 0; j < 4; ++j){
      bf8_t vf0 = *(const bf8_t*)&Vt[j*16 + c][kg*8];
      bf8_t vf1 = *(const bf8_t*)&Vt[j*16 + c][kg*8 + 32];
      mfma_acc(acc[j], pf0, vf0);
      mfma_acc(acc[j], pf1, vf1);
    }
  }

  const int base = ((b*8 + h)*7 + sp)*49;
  #pragma unroll
  for (int r = 0; r < 4; ++r){
    const int a = w*16 + 4*kg + r;
    if (a < 49){
      float* dst = pacc + (size_t)(base + a)*64 + c;
      #pragma unroll
      for (int j = 0; j < 4; ++j) dst[16*j] = acc[j][r];
    }
  }
  if (kg == 0 && areal){
    pml[(base + aw)*2]     = m_;
    pml[(base + aw)*2 + 1] = l_;
  }
}

// ---------------- merge the 7 partial softmax states -> agent_v ----------------
__global__ void k_merge(const float* __restrict__ pacc, const float* __restrict__ pml,
                        float* __restrict__ agentv){
  const int gw = blockIdx.x*4 + (threadIdx.x >> 6);
  const int lane = threadIdx.x & 63;
  if (gw >= 16*8*49) return;
  const int a = gw % 49, bh = gw / 49;
  float ms[7], ls[7], M = -1e30f;
  #pragma unroll
  for (int s = 0; s < 7; ++s){
    int base = (bh*7 + s)*49 + a;
    ms[s] = pml[base*2]; ls[s] = pml[base*2 + 1];
    M = fmaxf(M, ms[s]);
  }
  float L = 0.f, o = 0.f;
  #pragma unroll
  for (int s = 0; s < 7; ++s){
    float e = __expf(ms[s] - M);
    L += ls[s]*e;
    o += pacc[(size_t)((bh*7 + s)*49 + a)*64 + lane]*e;
  }
  agentv[(size_t)(bh*49 + a)*64 + lane] = o / L;
}

// ---------------- s2: q attention via MFMA ----------------
// grid 128*13; wave w owns pixel tile ti = (blk%13)*4 + w (64 px).
// S^T[64ag x 16px] = ag . q^T (q B-frags loaded direct from global);
// softmax over agents in-lane(i,r)+shfl(kg); P via wave-local LDS transpose;
// out[16px x 64d] = P . avT. avT zero-padded to 64 agents.
__global__ __launch_bounds__(256) void k_attn2(const unsigned short* __restrict__ qkv,
    const float* __restrict__ agent, const float* __restrict__ agentv,
    const float* __restrict__ absumT, unsigned short* __restrict__ outb){
  const int blk = blockIdx.x;
  const int bh = blk / 13, tloc = blk % 13;
  const int b = bh >> 3, h = bh & 7;
  const int tid = threadIdx.x, lane = tid & 63, w = tid >> 6;
  const int c = lane & 15, kg = lane >> 4;

  __shared__ unsigned short ag[64][72];       // scaled agents [agent][d], rows 49..63 zero
  __shared__ unsigned short avT[64][72];      // agent_v^T [d][agent], cols 49..63 zero
  __shared__ unsigned short Pl[4][16][72];    // per-wave P [pix][agent]

  for (int it = tid; it < 64*8; it += 256){
    int a = it >> 3, o = it & 7;
    u32x4 wv = {0,0,0,0};
    if (a < 49){
      const float* p = agent + ((size_t)b*49 + a)*512 + h*64 + o*8;
      f32x4 lo = *(const f32x4*)p, hi = *(const f32x4*)(p+4);
      wv.x = pack2(lo.x*QSCALE, lo.y*QSCALE);
      wv.y = pack2(lo.z*QSCALE, lo.w*QSCALE);
      wv.z = pack2(hi.x*QSCALE, hi.y*QSCALE);
      wv.w = pack2(hi.z*QSCALE, hi.w*QSCALE);
    }
    *(u32x4*)&ag[a][o*8] = wv;
  }
  for (int it = tid; it < 64*64; it += 256){
    int a = it >> 6, d = it & 63;
    avT[d][a] = (a < 49) ? f2bf(agentv[((size_t)bh*49 + a)*64 + d]) : (unsigned short)0;
  }
  __syncthreads();

  const int ti = tloc*4 + w;
  if (ti >= 49) return;
  const int pix0 = ti*64;

  // hoist A-frags (agents)
  bf8_t af[4][2];
  #pragma unroll
  for (int i = 0; i < 4; ++i){
    af[i][0] = *(const bf8_t*)&ag[i*16 + c][kg*8];
    af[i][1] = *(const bf8_t*)&ag[i*16 + c][kg*8 + 32];
  }

  for (int j = 0; j < 4; ++j){
    const int pix = pix0 + 16*j + c;    // this lane's pixel (B-col)
    const unsigned short* qp = qkv + ((size_t)b*3136 + pix)*1536 + h*64;
    bf8_t qf0 = *(const bf8_t*)(qp + kg*8);
    bf8_t qf1 = *(const bf8_t*)(qp + kg*8 + 32);
    f32x4 sa[4] = {};
    #pragma unroll
    for (int i = 0; i < 4; ++i){
      mfma_acc(sa[i], af[i][0], qf0);
      mfma_acc(sa[i], af[i][1], qf1);
    }
    // bias + mask padded agents, softmax over agents (in-lane 16 + kg shfl)
    float s16[4][4]; float mx = -1e30f;
    #pragma unroll
    for (int i = 0; i < 4; ++i){
      #pragma unroll
      for (int r = 0; r < 4; ++r){
        int a = 16*i + 4*kg + r;
        int am = a < 49 ? a : 48;
        float bias = absumT[((size_t)h*49 + am)*3136 + pix];
        float sv = (a < 49) ? (sa[i][r] + bias) : -1e30f;
        s16[i][r] = sv; mx = fmaxf(mx, sv);
      }
    }
    mx = fmaxf(mx, __shfl_xor(mx, 16));
    mx = fmaxf(mx, __shfl_xor(mx, 32));
    float rs = 0.f;
    #pragma unroll
    for (int i = 0; i < 4; ++i){
      #pragma unroll
      for (int r = 0; r < 4; ++r){
        float p = __expf(s16[i][r] - mx);
        s16[i][r] = p; rs += p;
      }
    }
    rs += __shfl_xor(rs, 16);
    rs += __shfl_xor(rs, 32);
    // P transpose via wave-local LDS: Pl[w][pixel c][agent]
    #pragma unroll
    for (int i = 0; i < 4; ++i){
      uint2 pw;
      pw.x = pack2(s16[i][0], s16[i][1]);
      pw.y = pack2(s16[i][2], s16[i][3]);
      *(uint2*)&Pl[w][c][16*i + 4*kg] = pw;
    }
    bf8_t pf0 = *(const bf8_t*)&Pl[w][c][kg*8];
    bf8_t pf1 = *(const bf8_t*)&Pl[w][c][kg*8 + 32];
    f32x4 acc[4] = {};
    #pragma unroll
    for (int jd = 0; jd < 4; ++jd){
      bf8_t vf0 = *(const bf8_t*)&avT[jd*16 + c][kg*8];
      bf8_t vf1 = *(const bf8_t*)&avT[jd*16 + c][kg*8 + 32];
      mfma_acc(acc[jd], pf0, vf0);
      mfma_acc(acc[jd], pf1, vf1);
    }
    // normalize rows by l (sum) of pixel 16j+4kg+r and store
    float l_s[4];
    #pragma unroll
    for (int r = 0; r < 4; ++r) l_s[r] = __shfl(rs, 4*kg + r);
    #pragma unroll
    for (int r = 0; r < 4; ++r){
      const int prow = pix0 + 16*j + 4*kg + r;
      unsigned short* op = outb + ((size_t)b*3136 + prow)*512 + h*64;
      float inv = 1.0f / l_s[r];
      #pragma unroll
      for (int jd = 0; jd < 4; ++jd)
        op[jd*16 + c] = f2bf(acc[jd][r] * inv);
    }
  }
}

// ---------------- depthwise 3x3 on v, RMW-add into outb ----------------
__global__ __launch_bounds__(256) void k_dwc(const unsigned short* __restrict__ qkv,
    const float* __restrict__ dwcw, const float* __restrict__ dwcb,
    unsigned short* __restrict__ outb){
  const int b = blockIdx.x / 56, y = blockIdx.x % 56;
  const int tid = threadIdx.x;
  const int cg = tid & 127, xh = tid >> 7;
  const int c0 = cg*4;
  float wv[9][4], bv[4];
  #pragma unroll
  for (int j = 0; j < 4; ++j){
    bv[j] = dwcb[c0 + j];
    #pragma unroll
    for (int t = 0; t < 9; ++t) wv[t][j] = dwcw[(c0 + j)*9 + t];
  }
  for (int xi = 0; xi < 28; ++xi){
    const int x = xh*28 + xi;
    float o[4] = {bv[0], bv[1], bv[2], bv[3]};
    #pragma unroll
    for (int ky = 0; ky < 3; ++ky){
      int ny = y + ky - 1;
      if (ny < 0 || ny >= 56) continue;
      #pragma unroll
      for (int kx = 0; kx < 3; ++kx){
        int nx = x + kx - 1;
        if (nx < 0 || nx >= 56) continue;
        const unsigned short* vp = qkv + ((size_t)b*3136 + ny*56 + nx)*1536 + 1024 + c0;
        unsigned int v01 = *(const unsigned int*)vp;
        unsigned int v23 = *((const unsigned int*)vp + 1);
        const int t = ky*3 + kx;
        o[0] += wv[t][0]*bflo(v01); o[1] += wv[t][1]*bfhi(v01);
        o[2] += wv[t][2]*bflo(v23); o[3] += wv[t][3]*bfhi(v23);
      }
    }
    unsigned short* op = outb + ((size_t)b*3136 + y*56 + x)*512 + c0;
    unsigned int a01 = *(unsigned int*)op;
    unsigned int a23 = *((unsigned int*)op + 1);
    o[0] += bflo(a01); o[1] += bfhi(a01);
    o[2] += bflo(a23); o[3] += bfhi(a23);
    *(unsigned int*)op       = pack2(o[0], o[1]);
    *((unsigned int*)op + 1) = pack2(o[2], o[3]);
  }
}

extern "C" void kernel_launch(void* const* d_in, const int* in_sizes, int n_in,
                              void* d_out, int out_size, void* d_ws, size_t ws_size,
                              hipStream_t stream){
  const float* x       = (const float*)d_in[0];
  const float* q_w     = (const float*)d_in[3];
  const float* q_b     = (const float*)d_in[4];
  const float* kv_w    = (const float*)d_in[5];
  const float* kv_b    = (const float*)d_in[6];
  const float* proj_w  = (const float*)d_in[7];
  const float* proj_b  = (const float*)d_in[8];
  const float* dwc_w   = (const float*)d_in[9];
  const float* dwc_b   = (const float*)d_in[10];
  const float* an_bias = (const float*)d_in[11];
  const float* na_bias = (const float*)d_in[12];
  const float* ah_bias = (const float*)d_in[13];
  const float* aw_bias = (const float*)d_in[14];
  const float* ha_bias = (const float*)d_in[15];
  const float* wa_bias = (const float*)d_in[16];

  char* ws = (char*)d_ws;
  size_t off = 0;
  auto alloc = [&](size_t bytes) -> void* {
    void* p = ws + off;
    off += (bytes + 255) & ~(size_t)255;
    return p;
  };
  unsigned short* xb     = (unsigned short*)alloc((size_t)50176*512*2);
  unsigned short* qkv    = (unsigned short*)alloc((size_t)50176*1536*2);
  unsigned short* wqkvt  = (unsigned short*)alloc((size_t)1536*512*2);
  unsigned short* wprojt = (unsigned short*)alloc((size_t)512*512*2);
  float* qkvb   = (float*)alloc((size_t)1536*4);
  float* agent  = (float*)alloc((size_t)16*49*512*4);
  float* agentv = (float*)alloc((size_t)16*8*49*64*4);
  float* pbs    = (float*)alloc((size_t)8*49*3136*4);
  float* absumT = (float*)alloc((size_t)8*49*3136*4);
  float* pacc   = (float*)alloc((size_t)16*8*8*49*64*4);
  float* pml    = (float*)alloc((size_t)16*8*8*49*2*4);
  unsigned short* outb = (unsigned short*)alloc((size_t)50176*512*2);
  if (off > ws_size) return;

  k_prep<<<512, 256, 0, stream>>>(q_w, kv_w, proj_w, q_b, kv_b, wqkvt, wprojt, qkvb);
  k_cvt_x<<<2048, 256, 0, stream>>>(x, xb);
  dim3 g1(12, 392);
  k_gemm<true><<<g1, 256, 0, stream>>>(xb, wqkvt, qkvb, qkv, 1536);
  k_pool<<<784, 256, 0, stream>>>(qkv, agent);
  k_pb<<<1024, 256, 0, stream>>>(an_bias, ah_bias, aw_bias, pbs);
  k_ab<<<1024, 256, 0, stream>>>(na_bias, ha_bias, wa_bias, absumT);
  k_attn1<<<896, 256, 0, stream>>>(qkv, agent, pbs, pacc, pml);
  k_merge<<<1568, 256, 0, stream>>>(pacc, pml, agentv);
  k_attn2<<<1664, 256, 0, stream>>>(qkv, agent, agentv, absumT, outb);
  k_dwc<<<896, 256, 0, stream>>>(qkv, dwc_w, dwc_b, outb);
  dim3 g2(4, 392);
  k_gemm<false><<<g2, 256, 0, stream>>>(outb, wprojt, proj_b, d_out, 512);
}

// Round 5
// 404.372 us; speedup vs baseline: 2.4745x; 1.0257x over previous
//
#include <hip/hip_runtime.h>
#include <hip/hip_bf16.h>

#define DEV __device__ __forceinline__

typedef __attribute__((ext_vector_type(4))) float f32x4;
typedef __attribute__((ext_vector_type(8))) short bf8_t;    // 8 bf16 = 4 VGPR
typedef __attribute__((ext_vector_type(4))) unsigned int u32x4;

// problem constants (fixed by setup_inputs)
static constexpr float QSCALE = 0.125f;   // dh^-0.5, dh=64

DEV float bflo(unsigned int w){ union{unsigned int i; float f;} x; x.i = w << 16; return x.f; }
DEV float bfhi(unsigned int w){ union{unsigned int i; float f;} x; x.i = w & 0xffff0000u; return x.f; }
DEV float bf2f(unsigned short u){ union{unsigned int i; float f;} x; x.i = ((unsigned int)u) << 16; return x.f; }
DEV unsigned short f2bf(float f){
  union{float f; unsigned int i;} x; x.f = f;
  unsigned int i = x.i;
  i += 0x7fffu + ((i >> 16) & 1u);   // round-to-nearest-even
  return (unsigned short)(i >> 16);
}
DEV unsigned int pack2(float a, float b){ return (unsigned int)f2bf(a) | ((unsigned int)f2bf(b) << 16); }

// inline-asm MFMA: D accumulates into C (tied operand)
DEV void mfma_acc(f32x4& c, const bf8_t& a, const bf8_t& b){
  asm volatile("v_mfma_f32_16x16x32_bf16 %0, %1, %2, %0" : "+v"(c) : "v"(a), "v"(b));
}

// async global->LDS 16B per lane: dst(lane) = l + lane*16 bytes (wave-uniform l)
DEV void cp16(unsigned short* l, const unsigned short* g){
  __builtin_amdgcn_global_load_lds(
      (const __attribute__((address_space(1))) unsigned int*)(const void*)g,
      (__attribute__((address_space(3))) unsigned int*)(void*)l, 16, 0, 0);
}

DEV float wred_max(float v){
  #pragma unroll
  for (int m = 1; m < 64; m <<= 1) v = fmaxf(v, __shfl_xor(v, m));
  return v;
}
DEV float wred_sum(float v){
  #pragma unroll
  for (int m = 1; m < 64; m <<= 1) v += __shfl_xor(v, m);
  return v;
}

// ---------------- prep: weight transpose+convert, bias concat ----------------
__global__ void k_prep(const float* __restrict__ qw, const float* __restrict__ kvw,
                       const float* __restrict__ pw, const float* __restrict__ qb,
                       const float* __restrict__ kvb,
                       unsigned short* __restrict__ wqkvt, unsigned short* __restrict__ wprojt,
                       float* __restrict__ qkvbias){
  const int i0 = blockIdx.x * blockDim.x + threadIdx.x;
  const int stride = gridDim.x * blockDim.x;
  for (int idx = i0; idx < 1536*512; idx += stride){
    int n = idx >> 9, k = idx & 511;
    float v = (n < 512) ? qw[k*512 + n] : kvw[k*1024 + (n - 512)];
    wqkvt[idx] = f2bf(v);                      // wqkvt[n][k]
  }
  for (int idx = i0; idx < 512*512; idx += stride){
    int n = idx >> 9, k = idx & 511;
    wprojt[idx] = f2bf(pw[k*512 + n]);         // wprojt[n][k]
  }
  for (int idx = i0; idx < 1536; idx += stride)
    qkvbias[idx] = (idx < 512) ? qb[idx] : kvb[idx - 512];
}

// ---------------- x -> bf16 ----------------
__global__ void k_cvt_x(const float* __restrict__ x, unsigned short* __restrict__ xb){
  const long total8 = (long)50176*512/8;
  for (long i = (long)blockIdx.x*blockDim.x + threadIdx.x; i < total8; i += (long)gridDim.x*blockDim.x){
    const float4* p = (const float4*)(x + i*8);
    float4 a = p[0], b = p[1];
    u32x4 o;
    o.x = pack2(a.x, a.y); o.y = pack2(a.z, a.w);
    o.z = pack2(b.x, b.y); o.w = pack2(b.z, b.w);
    *(u32x4*)(xb + i*8) = o;
  }
}

// ---------------- GEMM: C[M,N] = A[M,512] * Bt[N,512]^T + bias ----------------
// m97-style: global_load_lds(16B) staging into linear LDS, 2 barriers/k-step.
// XCD-grouped flat grid: each XCD walks one M-row across its N-blocks (A-panel
// stays L2-resident; requires gridDim % 8 == 0, true since 392 % 8 == 0).
template<bool OUT_BF>
__global__ __launch_bounds__(256) void k_gemm(const unsigned short* __restrict__ A,
    const unsigned short* __restrict__ Bt, const float* __restrict__ bias,
    void* __restrict__ Cp, const int N, const int nxb){
  __shared__ unsigned short Al[128][32];
  __shared__ unsigned short Bl[128][32];
  const int tid = threadIdx.x, lane = tid & 63, w = tid >> 6;
  const int bid = blockIdx.x;
  const int cxd = bid & 7, kk = bid >> 3;
  const int yi = kk / nxb, xb = kk - yi*nxb;
  const int m0 = (cxd + 8*yi) * 128, n0 = xb * 128;
  const int wr = (w >> 1) * 64, wc = (w & 1) * 64;
  const int fr = lane & 15, kg = lane >> 4;
  const int srow = lane >> 2, sp = lane & 3;       // staging row/slot within 16-row chunk

  // per-wave staging pointers: wave w stages A rows [32w,32w+32) and B rows [32w,32w+32)
  const unsigned short* gA0 = A  + (size_t)(m0 + w*32 + srow)*512 + sp*8;
  const unsigned short* gA1 = gA0 + (size_t)16*512;
  const unsigned short* gB0 = Bt + (size_t)(n0 + w*32 + srow)*512 + sp*8;
  const unsigned short* gB1 = gB0 + (size_t)16*512;
  unsigned short* lA0 = &Al[w*32][0];
  unsigned short* lA1 = &Al[w*32 + 16][0];
  unsigned short* lB0 = &Bl[w*32][0];
  unsigned short* lB1 = &Bl[w*32 + 16][0];

  f32x4 acc[4][4] = {};
  for (int kt = 0; kt < 16; ++kt){
    const int k0 = kt * 32;
    __syncthreads();
    cp16(lA0, gA0 + k0);
    cp16(lA1, gA1 + k0);
    cp16(lB0, gB0 + k0);
    cp16(lB1, gB1 + k0);
    __syncthreads();
    bf8_t af[4], bfm[4];
    #pragma unroll
    for (int i = 0; i < 4; ++i){
      af[i]  = *(const bf8_t*)&Al[wr + i*16 + fr][kg*8];
      bfm[i] = *(const bf8_t*)&Bl[wc + i*16 + fr][kg*8];
    }
    #pragma unroll
    for (int i = 0; i < 4; ++i)
      #pragma unroll
      for (int j = 0; j < 4; ++j)
        mfma_acc(acc[i][j], af[i], bfm[j]);
  }
  const int rb = (lane >> 4) * 4;
  #pragma unroll
  for (int j = 0; j < 4; ++j){
    const int col = n0 + wc + j*16 + fr;
    const float bs = bias[col];
    #pragma unroll
    for (int i = 0; i < 4; ++i){
      #pragma unroll
      for (int r = 0; r < 4; ++r){
        const int row = m0 + wr + i*16 + rb + r;
        float v = acc[i][j][r] + bs;
        if (OUT_BF) ((unsigned short*)Cp)[(size_t)row*N + col] = f2bf(v);
        else        ((float*)Cp)[(size_t)row*N + col] = v;
      }
    }
  }
}

// ---------------- agent pooling: 8x8 mean of q ----------------
__global__ void k_pool(const unsigned short* __restrict__ qkv, float* __restrict__ agent){
  const int b = blockIdx.x / 49, a = blockIdx.x % 49;
  const int p1 = a / 7, p2 = a % 7;
  for (int c = threadIdx.x; c < 512; c += 256){
    float s = 0.f;
    for (int r = 0; r < 8; ++r)
      for (int cc = 0; cc < 8; ++cc){
        int pix = (p1*8 + r)*56 + p2*8 + cc;
        s += bf2f(qkv[((size_t)b*3136 + pix)*1536 + c]);
      }
    agent[((size_t)b*49 + a)*512 + c] = s * (1.0f/64.0f);
  }
}

// ---------------- bilinear 7->56 helper ----------------
DEV void lin_w(int o, int& i0, int& i1, float& w){
  float src = (o + 0.5f)*0.125f - 0.5f;
  src = fmaxf(src, 0.f);
  int f = (int)floorf(src);
  i0 = min(f, 6); i1 = min(i0 + 1, 6); w = src - (float)i0;
}

__global__ void k_pb(const float* __restrict__ an, const float* __restrict__ ahb,
                     const float* __restrict__ awb, float* __restrict__ pbs){
  const int tot = 8*49*3136;
  for (int idx = blockIdx.x*blockDim.x + threadIdx.x; idx < tot; idx += gridDim.x*blockDim.x){
    int n = idx % 3136, ha = idx / 3136;
    int y = n / 56, x = n % 56;
    int iy0, iy1, ix0, ix1; float wy, wx;
    lin_w(y, iy0, iy1, wy); lin_w(x, ix0, ix1, wx);
    const float* t = an + (size_t)ha*49;
    float v0 = t[iy0*7+ix0]*(1.f-wy) + t[iy1*7+ix0]*wy;
    float v1 = t[iy0*7+ix1]*(1.f-wy) + t[iy1*7+ix1]*wy;
    float v = v0*(1.f-wx) + v1*wx;
    pbs[idx] = v + ahb[ha*56 + y] + awb[ha*56 + x];
  }
}

// absumT[h][agent][pix]  (transposed layout: coalesced for MFMA-attn2 bias reads)
__global__ void k_ab(const float* __restrict__ na, const float* __restrict__ hab,
                     const float* __restrict__ wab, float* __restrict__ absumT){
  const int tot = 8*49*3136;
  for (int idx = blockIdx.x*blockDim.x + threadIdx.x; idx < tot; idx += gridDim.x*blockDim.x){
    int n = idx % 3136, ha = idx / 3136;
    int a = ha % 49, h = ha / 49;
    int y = n / 56, x = n % 56;
    int iy0, iy1, ix0, ix1; float wy, wx;
    lin_w(y, iy0, iy1, wy); lin_w(x, ix0, ix1, wx);
    const float* t = na + (size_t)ha*49;
    float v0 = t[iy0*7+ix0]*(1.f-wy) + t[iy1*7+ix0]*wy;
    float v1 = t[iy0*7+ix1]*(1.f-wy) + t[iy1*7+ix1]*wy;
    float v = v0*(1.f-wx) + v1*wx;
    absumT[idx] = v + hab[(h*56+y)*49 + a] + wab[(h*56+x)*49 + a];
  }
}

// ---------------- s1: agent attention via MFMA, flash over n, split 7 ----------------
__global__ __launch_bounds__(256) void k_attn1(const unsigned short* __restrict__ qkv,
    const float* __restrict__ agent, const float* __restrict__ pbs,
    float* __restrict__ pacc, float* __restrict__ pml){
  const int bi = blockIdx.x;
  const int sp = bi % 7, h = (bi/7) & 7, b = bi / 56;
  const int tid = threadIdx.x, lane = tid & 63, w = tid >> 6;
  const int c = lane & 15, kg = lane >> 4;

  __shared__ unsigned short ag[64][72];
  __shared__ unsigned short Kl[64][72];
  __shared__ unsigned short Vt[64][72];
  __shared__ unsigned short Pl[4][16][72];

  for (int it = tid; it < 64*8; it += 256){
    int a = it >> 3, o = it & 7;
    u32x4 wv = {0,0,0,0};
    if (a < 49){
      const float* p = agent + ((size_t)b*49 + a)*512 + h*64 + o*8;
      f32x4 lo = *(const f32x4*)p, hi = *(const f32x4*)(p+4);
      wv.x = pack2(lo.x*QSCALE, lo.y*QSCALE);
      wv.y = pack2(lo.z*QSCALE, lo.w*QSCALE);
      wv.z = pack2(hi.x*QSCALE, hi.y*QSCALE);
      wv.w = pack2(hi.z*QSCALE, hi.w*QSCALE);
    }
    *(u32x4*)&ag[a][o*8] = wv;
  }
  __syncthreads();
  bf8_t agf[2];
  agf[0] = *(const bf8_t*)&ag[w*16 + c][kg*8];
  agf[1] = *(const bf8_t*)&ag[w*16 + c][kg*8 + 32];

  const int aw = w*16 + c;
  const int amin = aw < 49 ? aw : 48;
  const bool areal = aw < 49;
  const float* pbrow = pbs + ((size_t)(h*49 + amin))*3136 + sp*448;

  float m_ = -1e30f, l_ = 0.f;
  f32x4 acc[4] = {};

  for (int t = 0; t < 7; ++t){
    const int gn0 = sp*448 + t*64;
    f32x4 pb4[4];
    #pragma unroll
    for (int i = 0; i < 4; ++i)
      pb4[i] = *(const f32x4*)(pbrow + t*64 + 16*i + 4*kg);

    __syncthreads();
    #pragma unroll
    for (int ii = 0; ii < 2; ++ii){
      int it = tid + ii*256;
      int pix = it >> 3, o = it & 7;
      const unsigned short* kp = qkv + ((size_t)b*3136 + gn0 + pix)*1536 + 512 + h*64 + o*8;
      *(u32x4*)&Kl[pix][o*8] = *(const u32x4*)kp;
    }
    #pragma unroll
    for (int ii = 0; ii < 2; ++ii){
      int it = tid + ii*256;
      int pix = it & 63, o = it >> 6;
      const unsigned short* vp = qkv + ((size_t)b*3136 + gn0 + pix)*1536 + 1024 + h*64 + o*8;
      u32x4 vv = *(const u32x4*)vp;
      unsigned int vals[4] = {vv.x, vv.y, vv.z, vv.w};
      #pragma unroll
      for (int q = 0; q < 4; ++q){
        Vt[o*8 + 2*q][pix]     = (unsigned short)(vals[q] & 0xffffu);
        Vt[o*8 + 2*q + 1][pix] = (unsigned short)(vals[q] >> 16);
      }
    }
    __syncthreads();

    f32x4 sa[4] = {};
    #pragma unroll
    for (int i = 0; i < 4; ++i){
      bf8_t kf0 = *(const bf8_t*)&Kl[i*16 + c][kg*8];
      bf8_t kf1 = *(const bf8_t*)&Kl[i*16 + c][kg*8 + 32];
      mfma_acc(sa[i], kf0, agf[0]);
      mfma_acc(sa[i], kf1, agf[1]);
    }

    float s16[4][4]; float mx = -1e30f;
    #pragma unroll
    for (int i = 0; i < 4; ++i)
      #pragma unroll
      for (int r = 0; r < 4; ++r){
        float sv = areal ? (sa[i][r] + pb4[i][r]) : -1e30f;
        s16[i][r] = sv; mx = fmaxf(mx, sv);
      }
    mx = fmaxf(mx, __shfl_xor(mx, 16));
    mx = fmaxf(mx, __shfl_xor(mx, 32));
    float mn = fmaxf(m_, mx);
    float al = __expf(m_ - mn);
    float rs = 0.f;
    #pragma unroll
    for (int i = 0; i < 4; ++i)
      #pragma unroll
      for (int r = 0; r < 4; ++r){
        float p = __expf(s16[i][r] - mn);
        s16[i][r] = p; rs += p;
      }
    rs += __shfl_xor(rs, 16);
    rs += __shfl_xor(rs, 32);
    m_ = mn; l_ = l_*al + rs;

    #pragma unroll
    for (int i = 0; i < 4; ++i){
      uint2 pw;
      pw.x = pack2(s16[i][0], s16[i][1]);
      pw.y = pack2(s16[i][2], s16[i][3]);
      *(uint2*)&Pl[w][c][16*i + 4*kg] = pw;
    }

    float al_s[4];
    #pragma unroll
    for (int r = 0; r < 4; ++r) al_s[r] = __shfl(al, 4*kg + r);
    #pragma unroll
    for (int j = 0; j < 4; ++j)
      #pragma unroll
      for (int r = 0; r < 4; ++r) acc[j][r] *= al_s[r];

    bf8_t pf0 = *(const bf8_t*)&Pl[w][c][kg*8];
    bf8_t pf1 = *(const bf8_t*)&Pl[w][c][kg*8 + 32];
    #pragma unroll
    for (int j = 0; j < 4; ++j){
      bf8_t vf0 = *(const bf8_t*)&Vt[j*16 + c][kg*8];
      bf8_t vf1 = *(const bf8_t*)&Vt[j*16 + c][kg*8 + 32];
      mfma_acc(acc[j], pf0, vf0);
      mfma_acc(acc[j], pf1, vf1);
    }
  }

  const int base = ((b*8 + h)*7 + sp)*49;
  #pragma unroll
  for (int r = 0; r < 4; ++r){
    const int a = w*16 + 4*kg + r;
    if (a < 49){
      float* dst = pacc + (size_t)(base + a)*64 + c;
      #pragma unroll
      for (int j = 0; j < 4; ++j) dst[16*j] = acc[j][r];
    }
  }
  if (kg == 0 && areal){
    pml[(base + aw)*2]     = m_;
    pml[(base + aw)*2 + 1] = l_;
  }
}

// ---------------- merge the 7 partial softmax states -> agent_v ----------------
__global__ void k_merge(const float* __restrict__ pacc, const float* __restrict__ pml,
                        float* __restrict__ agentv){
  const int gw = blockIdx.x*4 + (threadIdx.x >> 6);
  const int lane = threadIdx.x & 63;
  if (gw >= 16*8*49) return;
  const int a = gw % 49, bh = gw / 49;
  float ms[7], ls[7], M = -1e30f;
  #pragma unroll
  for (int s = 0; s < 7; ++s){
    int base = (bh*7 + s)*49 + a;
    ms[s] = pml[base*2]; ls[s] = pml[base*2 + 1];
    M = fmaxf(M, ms[s]);
  }
  float L = 0.f, o = 0.f;
  #pragma unroll
  for (int s = 0; s < 7; ++s){
    float e = __expf(ms[s] - M);
    L += ls[s]*e;
    o += pacc[(size_t)((bh*7 + s)*49 + a)*64 + lane]*e;
  }
  agentv[(size_t)(bh*49 + a)*64 + lane] = o / L;
}

// ---------------- s2: q attention via MFMA ----------------
__global__ __launch_bounds__(256) void k_attn2(const unsigned short* __restrict__ qkv,
    const float* __restrict__ agent, const float* __restrict__ agentv,
    const float* __restrict__ absumT, unsigned short* __restrict__ outb){
  const int blk = blockIdx.x;
  const int bh = blk / 13, tloc = blk % 13;
  const int b = bh >> 3, h = bh & 7;
  const int tid = threadIdx.x, lane = tid & 63, w = tid >> 6;
  const int c = lane & 15, kg = lane >> 4;

  __shared__ unsigned short ag[64][72];       // scaled agents [agent][d], rows 49..63 zero
  __shared__ unsigned short avT[64][72];      // agent_v^T [d][agent], cols 49..63 zero
  __shared__ unsigned short Pl[4][16][72];    // per-wave P [pix][agent]

  for (int it = tid; it < 64*8; it += 256){
    int a = it >> 3, o = it & 7;
    u32x4 wv = {0,0,0,0};
    if (a < 49){
      const float* p = agent + ((size_t)b*49 + a)*512 + h*64 + o*8;
      f32x4 lo = *(const f32x4*)p, hi = *(const f32x4*)(p+4);
      wv.x = pack2(lo.x*QSCALE, lo.y*QSCALE);
      wv.y = pack2(lo.z*QSCALE, lo.w*QSCALE);
      wv.z = pack2(hi.x*QSCALE, hi.y*QSCALE);
      wv.w = pack2(hi.z*QSCALE, hi.w*QSCALE);
    }
    *(u32x4*)&ag[a][o*8] = wv;
  }
  for (int it = tid; it < 64*64; it += 256){
    int a = it >> 6, d = it & 63;
    avT[d][a] = (a < 49) ? f2bf(agentv[((size_t)bh*49 + a)*64 + d]) : (unsigned short)0;
  }
  __syncthreads();

  const int ti = tloc*4 + w;
  if (ti >= 49) return;
  const int pix0 = ti*64;

  bf8_t af[4][2];
  #pragma unroll
  for (int i = 0; i < 4; ++i){
    af[i][0] = *(const bf8_t*)&ag[i*16 + c][kg*8];
    af[i][1] = *(const bf8_t*)&ag[i*16 + c][kg*8 + 32];
  }

  for (int j = 0; j < 4; ++j){
    const int pix = pix0 + 16*j + c;    // this lane's pixel (B-col)
    const unsigned short* qp = qkv + ((size_t)b*3136 + pix)*1536 + h*64;
    bf8_t qf0 = *(const bf8_t*)(qp + kg*8);
    bf8_t qf1 = *(const bf8_t*)(qp + kg*8 + 32);
    f32x4 sa[4] = {};
    #pragma unroll
    for (int i = 0; i < 4; ++i){
      mfma_acc(sa[i], af[i][0], qf0);
      mfma_acc(sa[i], af[i][1], qf1);
    }
    float s16[4][4]; float mx = -1e30f;
    #pragma unroll
    for (int i = 0; i < 4; ++i){
      #pragma unroll
      for (int r = 0; r < 4; ++r){
        int a = 16*i + 4*kg + r;
        int am = a < 49 ? a : 48;
        float bias = absumT[((size_t)h*49 + am)*3136 + pix];
        float sv = (a < 49) ? (sa[i][r] + bias) : -1e30f;
        s16[i][r] = sv; mx = fmaxf(mx, sv);
      }
    }
    mx = fmaxf(mx, __shfl_xor(mx, 16));
    mx = fmaxf(mx, __shfl_xor(mx, 32));
    float rs = 0.f;
    #pragma unroll
    for (int i = 0; i < 4; ++i){
      #pragma unroll
      for (int r = 0; r < 4; ++r){
        float p = __expf(s16[i][r] - mx);
        s16[i][r] = p; rs += p;
      }
    }
    rs += __shfl_xor(rs, 16);
    rs += __shfl_xor(rs, 32);
    #pragma unroll
    for (int i = 0; i < 4; ++i){
      uint2 pw;
      pw.x = pack2(s16[i][0], s16[i][1]);
      pw.y = pack2(s16[i][2], s16[i][3]);
      *(uint2*)&Pl[w][c][16*i + 4*kg] = pw;
    }
    bf8_t pf0 = *(const bf8_t*)&Pl[w][c][kg*8];
    bf8_t pf1 = *(const bf8_t*)&Pl[w][c][kg*8 + 32];
    f32x4 acc[4] = {};
    #pragma unroll
    for (int jd = 0; jd < 4; ++jd){
      bf8_t vf0 = *(const bf8_t*)&avT[jd*16 + c][kg*8];
      bf8_t vf1 = *(const bf8_t*)&avT[jd*16 + c][kg*8 + 32];
      mfma_acc(acc[jd], pf0, vf0);
      mfma_acc(acc[jd], pf1, vf1);
    }
    float l_s[4];
    #pragma unroll
    for (int r = 0; r < 4; ++r) l_s[r] = __shfl(rs, 4*kg + r);
    #pragma unroll
    for (int r = 0; r < 4; ++r){
      const int prow = pix0 + 16*j + 4*kg + r;
      unsigned short* op = outb + ((size_t)b*3136 + prow)*512 + h*64;
      float inv = 1.0f / l_s[r];
      #pragma unroll
      for (int jd = 0; jd < 4; ++jd)
        op[jd*16 + c] = f2bf(acc[jd][r] * inv);
    }
  }
}

// ---------------- depthwise 3x3 on v, RMW-add into outb ----------------
__global__ __launch_bounds__(256) void k_dwc(const unsigned short* __restrict__ qkv,
    const float* __restrict__ dwcw, const float* __restrict__ dwcb,
    unsigned short* __restrict__ outb){
  const int b = blockIdx.x / 56, y = blockIdx.x % 56;
  const int tid = threadIdx.x;
  const int cg = tid & 127, xh = tid >> 7;
  const int c0 = cg*4;
  float wv[9][4], bv[4];
  #pragma unroll
  for (int j = 0; j < 4; ++j){
    bv[j] = dwcb[c0 + j];
    #pragma unroll
    for (int t = 0; t < 9; ++t) wv[t][j] = dwcw[(c0 + j)*9 + t];
  }
  for (int xi = 0; xi < 28; ++xi){
    const int x = xh*28 + xi;
    float o[4] = {bv[0], bv[1], bv[2], bv[3]};
    #pragma unroll
    for (int ky = 0; ky < 3; ++ky){
      int ny = y + ky - 1;
      if (ny < 0 || ny >= 56) continue;
      #pragma unroll
      for (int kx = 0; kx < 3; ++kx){
        int nx = x + kx - 1;
        if (nx < 0 || nx >= 56) continue;
        const unsigned short* vp = qkv + ((size_t)b*3136 + ny*56 + nx)*1536 + 1024 + c0;
        unsigned int v01 = *(const unsigned int*)vp;
        unsigned int v23 = *((const unsigned int*)vp + 1);
        const int t = ky*3 + kx;
        o[0] += wv[t][0]*bflo(v01); o[1] += wv[t][1]*bfhi(v01);
        o[2] += wv[t][2]*bflo(v23); o[3] += wv[t][3]*bfhi(v23);
      }
    }
    unsigned short* op = outb + ((size_t)b*3136 + y*56 + x)*512 + c0;
    unsigned int a01 = *(unsigned int*)op;
    unsigned int a23 = *((unsigned int*)op + 1);
    o[0] += bflo(a01); o[1] += bfhi(a01);
    o[2] += bflo(a23); o[3] += bfhi(a23);
    *(unsigned int*)op       = pack2(o[0], o[1]);
    *((unsigned int*)op + 1) = pack2(o[2], o[3]);
  }
}

extern "C" void kernel_launch(void* const* d_in, const int* in_sizes, int n_in,
                              void* d_out, int out_size, void* d_ws, size_t ws_size,
                              hipStream_t stream){
  const float* x       = (const float*)d_in[0];
  const float* q_w     = (const float*)d_in[3];
  const float* q_b     = (const float*)d_in[4];
  const float* kv_w    = (const float*)d_in[5];
  const float* kv_b    = (const float*)d_in[6];
  const float* proj_w  = (const float*)d_in[7];
  const float* proj_b  = (const float*)d_in[8];
  const float* dwc_w   = (const float*)d_in[9];
  const float* dwc_b   = (const float*)d_in[10];
  const float* an_bias = (const float*)d_in[11];
  const float* na_bias = (const float*)d_in[12];
  const float* ah_bias = (const float*)d_in[13];
  const float* aw_bias = (const float*)d_in[14];
  const float* ha_bias = (const float*)d_in[15];
  const float* wa_bias = (const float*)d_in[16];

  char* ws = (char*)d_ws;
  size_t off = 0;
  auto alloc = [&](size_t bytes) -> void* {
    void* p = ws + off;
    off += (bytes + 255) & ~(size_t)255;
    return p;
  };
  unsigned short* xb     = (unsigned short*)alloc((size_t)50176*512*2);
  unsigned short* qkv    = (unsigned short*)alloc((size_t)50176*1536*2);
  unsigned short* wqkvt  = (unsigned short*)alloc((size_t)1536*512*2);
  unsigned short* wprojt = (unsigned short*)alloc((size_t)512*512*2);
  float* qkvb   = (float*)alloc((size_t)1536*4);
  float* agent  = (float*)alloc((size_t)16*49*512*4);
  float* agentv = (float*)alloc((size_t)16*8*49*64*4);
  float* pbs    = (float*)alloc((size_t)8*49*3136*4);
  float* absumT = (float*)alloc((size_t)8*49*3136*4);
  float* pacc   = (float*)alloc((size_t)16*8*8*49*64*4);
  float* pml    = (float*)alloc((size_t)16*8*8*49*2*4);
  unsigned short* outb = (unsigned short*)alloc((size_t)50176*512*2);
  if (off > ws_size) return;

  k_prep<<<512, 256, 0, stream>>>(q_w, kv_w, proj_w, q_b, kv_b, wqkvt, wprojt, qkvb);
  k_cvt_x<<<2048, 256, 0, stream>>>(x, xb);
  k_gemm<true><<<4704, 256, 0, stream>>>(xb, wqkvt, qkvb, qkv, 1536, 12);
  k_pool<<<784, 256, 0, stream>>>(qkv, agent);
  k_pb<<<1024, 256, 0, stream>>>(an_bias, ah_bias, aw_bias, pbs);
  k_ab<<<1024, 256, 0, stream>>>(na_bias, ha_bias, wa_bias, absumT);
  k_attn1<<<896, 256, 0, stream>>>(qkv, agent, pbs, pacc, pml);
  k_merge<<<1568, 256, 0, stream>>>(pacc, pml, agentv);
  k_attn2<<<1664, 256, 0, stream>>>(qkv, agent, agentv, absumT, outb);
  k_dwc<<<896, 256, 0, stream>>>(qkv, dwc_w, dwc_b, outb);
  k_gemm<false><<<1568, 256, 0, stream>>>(outb, wprojt, proj_b, d_out, 512, 4);
}